// Round 4
// baseline (460.783 us; speedup 1.0000x reference)
//
#include <hip/hip_runtime.h>
#include <math.h>

#define N_NODES 10000
#define N_EDGES 160000
#define N_FEAT  512
#define HEADS   8
#define HID     128

typedef __attribute__((ext_vector_type(8))) short bf16x8;
typedef __attribute__((ext_vector_type(4))) float f32x4;

// ---------------------------------------------------------------------------
// fp32 <-> bf16 helpers
// ---------------------------------------------------------------------------
__device__ inline unsigned short f2bf_rne(float f) {
  unsigned int u = __float_as_uint(f);
  unsigned int r = u + 0x7fffu + ((u >> 16) & 1u);
  return (unsigned short)(r >> 16);
}
__device__ inline float bf2f(unsigned int b) {
  return __uint_as_float(b << 16);
}

__global__ __launch_bounds__(256)
void split_kernel(const float* __restrict__ in, unsigned short* __restrict__ hi,
                  unsigned short* __restrict__ lo, int n4) {
  int i = blockIdx.x * blockDim.x + threadIdx.x;
  if (i >= n4) return;
  float4 v = ((const float4*)in)[i];
  ushort4 h, l;
  h.x = f2bf_rne(v.x); l.x = f2bf_rne(v.x - bf2f(h.x));
  h.y = f2bf_rne(v.y); l.y = f2bf_rne(v.y - bf2f(h.y));
  h.z = f2bf_rne(v.z); l.z = f2bf_rne(v.z - bf2f(h.z));
  h.w = f2bf_rne(v.w); l.w = f2bf_rne(v.w - bf2f(h.w));
  ((ushort4*)hi)[i] = h;
  ((ushort4*)lo)[i] = l;
}

// ---------------------------------------------------------------------------
// Split-bf16 MFMA GEMM (3-term). 128x128 tile / 256 threads.
// Epilogue also writes hb[head][row][d] (bf16, head-major) for the gather path.
// Each blockIdx.x covers exactly one head (O-tile 128 == HID).
// ---------------------------------------------------------------------------
#define GM 128
#define GN 128
#define GK 32
#define AST 40

__global__ __launch_bounds__(256)
void gemm_mfma_split(const unsigned short* __restrict__ Ahi,
                     const unsigned short* __restrict__ Alo,
                     const unsigned short* __restrict__ Bhi,
                     const unsigned short* __restrict__ Blo,
                     float* __restrict__ C, unsigned short* __restrict__ hb,
                     int M, int K, int O) {
  __shared__ unsigned short sA[2][GM * AST];
  __shared__ unsigned short sB[2][GN * AST];
  int tid = threadIdx.x;
  int wave = tid >> 6, lane = tid & 63;
  int m0 = blockIdx.y * GM, n0 = blockIdx.x * GN;
  int wm = (wave & 1) * 64, wn = (wave >> 1) * 64;
  int r = lane & 15, q = lane >> 4;

  f32x4 acc[4][4] = {};

  for (int k0 = 0; k0 < K; k0 += GK) {
    #pragma unroll
    for (int t = 0; t < 2; ++t) {
      int idx = tid + t * 256;
      int row = idx >> 2, kq = idx & 3;
      int arow = m0 + row; if (arow >= M) arow = M - 1;
      size_t ga = (size_t)arow * K + k0 + kq * 8;
      int4 vhi = *(const int4*)&Ahi[ga];
      int4 vlo = *(const int4*)&Alo[ga];
      int la = row * AST + kq * 8;
      *(int4*)&sA[0][la] = vhi;
      *(int4*)&sA[1][la] = vlo;
      size_t gb = (size_t)(n0 + row) * K + k0 + kq * 8;
      int4 whi = *(const int4*)&Bhi[gb];
      int4 wlo = *(const int4*)&Blo[gb];
      *(int4*)&sB[0][la] = whi;
      *(int4*)&sB[1][la] = wlo;
    }
    __syncthreads();
    bf16x8 ah[4], al[4], bh[4], bl[4];
    #pragma unroll
    for (int i = 0; i < 4; ++i) {
      int ra = (wm + i * 16 + r) * AST + q * 8;
      ah[i] = *(const bf16x8*)&sA[0][ra];
      al[i] = *(const bf16x8*)&sA[1][ra];
      int rb = (wn + i * 16 + r) * AST + q * 8;
      bh[i] = *(const bf16x8*)&sB[0][rb];
      bl[i] = *(const bf16x8*)&sB[1][rb];
    }
    #pragma unroll
    for (int i = 0; i < 4; ++i)
      #pragma unroll
      for (int j = 0; j < 4; ++j) {
        acc[i][j] = __builtin_amdgcn_mfma_f32_16x16x32_bf16(ah[i], bh[j], acc[i][j], 0, 0, 0);
        acc[i][j] = __builtin_amdgcn_mfma_f32_16x16x32_bf16(ah[i], bl[j], acc[i][j], 0, 0, 0);
        acc[i][j] = __builtin_amdgcn_mfma_f32_16x16x32_bf16(al[i], bh[j], acc[i][j], 0, 0, 0);
      }
    __syncthreads();
  }
  // C/D layout: col = lane&15, row = (lane>>4)*4 + reg
  int head = blockIdx.x;  // GN == HID
  #pragma unroll
  for (int i = 0; i < 4; ++i) {
    #pragma unroll
    for (int reg = 0; reg < 4; ++reg) {
      int row = m0 + wm + i * 16 + q * 4 + reg;
      if (row < M) {
        #pragma unroll
        for (int j = 0; j < 4; ++j) {
          float v = acc[i][j][reg];
          int d = wn + j * 16 + r;
          C[(size_t)row * O + n0 + d] = v;
          hb[((size_t)head * M + row) * HID + d] = f2bf_rne(v);
        }
      }
    }
  }
}

// ---------------------------------------------------------------------------
// CSR build
// ---------------------------------------------------------------------------
__global__ void count_kernel(const int* __restrict__ dst, int* __restrict__ deg, int E) {
  int e = blockIdx.x * blockDim.x + threadIdx.x;
  if (e < E) atomicAdd(&deg[dst[e]], 1);
}

__global__ __launch_bounds__(1024)
void scan_kernel(const int* __restrict__ deg, int* __restrict__ off, int N) {
  __shared__ int sums[1024];
  const int PER = 10;
  int tid = threadIdx.x;
  int base = tid * PER;
  int loc[PER];
  int run = 0;
  #pragma unroll
  for (int j = 0; j < PER; ++j) {
    int v = (base + j < N) ? deg[base + j] : 0;
    run += v;
    loc[j] = run;
  }
  sums[tid] = run;
  __syncthreads();
  for (int o = 1; o < 1024; o <<= 1) {
    int v = (tid >= o) ? sums[tid - o] : 0;
    __syncthreads();
    sums[tid] += v;
    __syncthreads();
  }
  int ex = sums[tid] - run;
  if (tid == 0) off[0] = 0;
  #pragma unroll
  for (int j = 0; j < PER; ++j)
    if (base + j < N) off[base + j + 1] = ex + loc[j];
}

__global__ void fill_kernel(const int* __restrict__ src, const int* __restrict__ dst,
                            const int* __restrict__ off, int* __restrict__ cursor,
                            int* __restrict__ ssrc, int E) {
  int e = blockIdx.x * blockDim.x + threadIdx.x;
  if (e < E) {
    int d = dst[e];
    int p = atomicAdd(&cursor[d], 1);
    ssrc[off[d] + p] = src[e];
  }
}

// ---------------------------------------------------------------------------
// Attention scores (reads fp32 h, [n][head*128+d] layout)
// ---------------------------------------------------------------------------
__global__ __launch_bounds__(256)
void scores_kernel(const float* __restrict__ h, const float* __restrict__ a,
                   float* __restrict__ si, float* __restrict__ sj, int NH) {
  int w = (blockIdx.x * blockDim.x + threadIdx.x) >> 6;
  int lane = threadIdx.x & 63;
  if (w >= NH) return;
  int head = w & (HEADS - 1);
  const float* hp = h + (size_t)w * HID;
  const float* ap = a + (size_t)head * (2 * HID);
  float v0 = hp[lane], v1 = hp[lane + 64];
  float psi = v0 * ap[lane] + v1 * ap[lane + 64];
  float psj = v0 * ap[HID + lane] + v1 * ap[HID + lane + 64];
  #pragma unroll
  for (int o = 32; o > 0; o >>= 1) {
    psi += __shfl_down(psi, o);
    psj += __shfl_down(psj, o);
  }
  if (lane == 0) { si[w] = psi; sj[w] = psj; }
}

// ---------------------------------------------------------------------------
// Edge softmax weights: one wave per dst node. Lane = eidx*8 + head.
// ---------------------------------------------------------------------------
__global__ __launch_bounds__(256)
void alpha_kernel(const float* __restrict__ si, const float* __restrict__ sj,
                  const int* __restrict__ off, const int* __restrict__ ssrc,
                  float* __restrict__ w, float* __restrict__ invden, int N) {
  int wv = (blockIdx.x * blockDim.x + threadIdx.x) >> 6;
  if (wv >= N) return;
  int lane = threadIdx.x & 63;
  int eidx = lane >> 3, head = lane & 7;
  int begin = off[wv], end = off[wv + 1];
  float s_i = si[wv * HEADS + head];

  float m = -INFINITY;
  for (int k0 = begin; k0 < end; k0 += 8) {
    int k = k0 + eidx;
    if (k < end) {
      float e = s_i + sj[ssrc[k] * HEADS + head];
      e = e > 0.f ? e : 0.01f * e;
      m = fmaxf(m, e);
    }
  }
  m = fmaxf(m, __shfl_xor(m, 8));
  m = fmaxf(m, __shfl_xor(m, 16));
  m = fmaxf(m, __shfl_xor(m, 32));

  float sum = 0.f;
  for (int k0 = begin; k0 < end; k0 += 8) {
    int k = k0 + eidx;
    if (k < end) {
      float e = s_i + sj[ssrc[k] * HEADS + head];
      e = e > 0.f ? e : 0.01f * e;
      float wt = expf(e - m);
      w[(size_t)k * HEADS + head] = wt;
      sum += wt;
    }
  }
  sum += __shfl_xor(sum, 8);
  sum += __shfl_xor(sum, 16);
  sum += __shfl_xor(sum, 32);
  if (eidx == 0)
    invden[wv * HEADS + head] = sum > 0.f ? 1.0f / sum : 0.f;
}

// ---------------------------------------------------------------------------
// Aggregation v2: one wave per (dst, head); head = blockIdx.x & 7 so that
// round-robin block->XCD dispatch gives each XCD (mostly) one head's 2.56 MB
// hb slice -> L2-resident gather. Writes per-head agg to aggbuf[head][n][d].
// ---------------------------------------------------------------------------
__global__ __launch_bounds__(512)
void gat_aggregate2(const unsigned short* __restrict__ hb,
                    const float* __restrict__ w, const float* __restrict__ invden,
                    const int* __restrict__ off, const int* __restrict__ ssrc,
                    float* __restrict__ aggbuf, int N) {
  int head = blockIdx.x & 7;
  int n = (blockIdx.x >> 3) * 8 + (threadIdx.x >> 6);
  if (n >= N) return;
  int lane = threadIdx.x & 63;
  const unsigned short* hbase = hb + (size_t)head * N * HID;
  int begin = off[n], end = off[n + 1];

  float ax = 0.f, ay = 0.f;
  int k = begin;
  for (; k + 1 < end; k += 2) {
    int s0 = ssrc[k], s1 = ssrc[k + 1];
    float w0 = w[(size_t)k * HEADS + head];
    float w1 = w[(size_t)(k + 1) * HEADS + head];
    unsigned int p0 = *(const unsigned int*)&hbase[(size_t)s0 * HID + lane * 2];
    unsigned int p1 = *(const unsigned int*)&hbase[(size_t)s1 * HID + lane * 2];
    ax = fmaf(w0, bf2f(p0 & 0xffffu), ax);
    ay = fmaf(w0, bf2f(p0 >> 16), ay);
    ax = fmaf(w1, bf2f(p1 & 0xffffu), ax);
    ay = fmaf(w1, bf2f(p1 >> 16), ay);
  }
  if (k < end) {
    int s0 = ssrc[k];
    float w0 = w[(size_t)k * HEADS + head];
    unsigned int p0 = *(const unsigned int*)&hbase[(size_t)s0 * HID + lane * 2];
    ax = fmaf(w0, bf2f(p0 & 0xffffu), ax);
    ay = fmaf(w0, bf2f(p0 >> 16), ay);
  }
  float inv = invden[n * HEADS + head];
  float2 o = make_float2(ax * inv, ay * inv);
  ((float2*)aggbuf)[((size_t)head * N + n) * 64 + lane] = o;
}

// ---------------------------------------------------------------------------
// Head mean + ELU: emb[n,d] = ELU(mean_h aggbuf[h][n][d])
// ---------------------------------------------------------------------------
__global__ __launch_bounds__(256)
void headmean_kernel(const float* __restrict__ aggbuf, float* __restrict__ emb, int N) {
  int i = blockIdx.x * blockDim.x + threadIdx.x;  // float2 index
  if (i >= N * 64) return;
  float sx = 0.f, sy = 0.f;
  #pragma unroll
  for (int hh = 0; hh < HEADS; ++hh) {
    float2 v = ((const float2*)aggbuf)[(size_t)hh * N * 64 + i];
    sx += v.x; sy += v.y;
  }
  sx *= (1.0f / HEADS); sy *= (1.0f / HEADS);
  float ox = sx > 0.f ? sx : (expf(sx) - 1.0f);
  float oy = sy > 0.f ? sy : (expf(sy) - 1.0f);
  ((float2*)emb)[i] = make_float2(ox, oy);
}

// ---------------------------------------------------------------------------
// Graph pooling
// ---------------------------------------------------------------------------
__global__ __launch_bounds__(256)
void pool_kernel(const float* __restrict__ emb, float* __restrict__ g, int N) {
  __shared__ float part[256];
  int d = threadIdx.x & 127;
  int half = threadIdx.x >> 7;
  int n0 = blockIdx.x * 100;
  float s = 0.f;
  for (int i = half; i < 100; i += 2) {
    int n = n0 + i;
    if (n < N) s += emb[(size_t)n * HID + d];
  }
  part[threadIdx.x] = s;
  __syncthreads();
  if (threadIdx.x < HID) atomicAdd(&g[d], part[threadIdx.x] + part[128 + threadIdx.x]);
}

// ---------------------------------------------------------------------------
// LayerNorm + MLP head
// ---------------------------------------------------------------------------
__global__ __launch_bounds__(128)
void mlp_kernel(const float* __restrict__ g, const float* __restrict__ ln_g,
                const float* __restrict__ ln_b, const float* __restrict__ Wl1,
                const float* __restrict__ bl1, const float* __restrict__ Wl2,
                const float* __restrict__ bl2, const float* __restrict__ Wl3,
                const float* __restrict__ bl3, float* __restrict__ out, float invN) {
  __shared__ float red[128];
  __shared__ float gn[128];
  __shared__ float x1[64];
  __shared__ float x2[16];
  int t = threadIdx.x;
  float gg = g[t] * invN;
  red[t] = gg;
  __syncthreads();
  for (int o = 64; o > 0; o >>= 1) {
    if (t < o) red[t] += red[t + o];
    __syncthreads();
  }
  float mu = red[0] * (1.0f / HID);
  __syncthreads();
  float dv = gg - mu;
  red[t] = dv * dv;
  __syncthreads();
  for (int o = 64; o > 0; o >>= 1) {
    if (t < o) red[t] += red[t + o];
    __syncthreads();
  }
  float var = red[0] * (1.0f / HID);
  gn[t] = dv / sqrtf(var + 1e-5f) * ln_g[t] + ln_b[t];
  __syncthreads();
  if (t < 64) {
    float s = bl1[t];
    for (int k = 0; k < 128; ++k) s += Wl1[t * 128 + k] * gn[k];
    x1[t] = s > 0.f ? s : 0.01f * s;
  }
  __syncthreads();
  if (t < 16) {
    float s = bl2[t];
    for (int k = 0; k < 64; ++k) s += Wl2[t * 64 + k] * x1[k];
    x2[t] = s > 0.f ? s : 0.01f * s;
  }
  __syncthreads();
  if (t < 16) {
    float s = bl3[t];
    for (int k = 0; k < 16; ++k) s += Wl3[t * 16 + k] * x2[k];
    out[t] = s > 0.f ? s : 0.f;
  }
}

// ---------------------------------------------------------------------------
extern "C" void kernel_launch(void* const* d_in, const int* in_sizes, int n_in,
                              void* d_out, int out_size, void* d_ws, size_t ws_size,
                              hipStream_t stream) {
  const float* x    = (const float*)d_in[0];
  const int*   esrc = (const int*)d_in[1];
  const int*   edst = (const int*)d_in[2];
  const float* W1   = (const float*)d_in[3];
  const float* a1   = (const float*)d_in[4];
  const float* W2   = (const float*)d_in[5];
  const float* a2   = (const float*)d_in[6];
  const float* ln_g = (const float*)d_in[7];
  const float* ln_b = (const float*)d_in[8];
  const float* Wl1  = (const float*)d_in[9];
  const float* bl1  = (const float*)d_in[10];
  const float* Wl2  = (const float*)d_in[11];
  const float* bl2  = (const float*)d_in[12];
  const float* Wl3  = (const float*)d_in[13];
  const float* bl3  = (const float*)d_in[14];
  float* out = (float*)d_out;

  float* ws   = (float*)d_ws;
  float* h    = ws;                                     // 10,240,000 f  (41 MB)
  float* aggbuf = h;                                    // ALIAS: h is dead after scores/alpha
  float* si   = h + (size_t)N_NODES * HEADS * HID;      // 80,000
  float* sj   = si + N_NODES * HEADS;                   // 80,000
  float* emb1 = sj + N_NODES * HEADS;                   // 1,280,000
  float* emb2 = emb1 + (size_t)N_NODES * HID;           // 1,280,000
  float* g    = emb2 + (size_t)N_NODES * HID;           // 128
  float* wbuf = g + 128;                                // 1,280,000
  float* invd = wbuf + (size_t)N_EDGES * HEADS;         // 80,000
  int*   deg  = (int*)(invd + N_NODES * HEADS);         // 10,000
  int*   off  = deg + N_NODES;                          // 10,001
  int*   ssrc = off + (N_NODES + 1);                    // 160,000
  unsigned short* sAhi = (unsigned short*)(ssrc + N_EDGES + 3);
  unsigned short* sAlo = sAhi + (size_t)N_NODES * N_FEAT;
  unsigned short* sBhi = sAlo + (size_t)N_NODES * N_FEAT;
  unsigned short* sBlo = sBhi + HEADS * HID * N_FEAT;
  unsigned short* hb   = sBlo + HEADS * HID * N_FEAT;   // 10,240,000 us (20.5 MB)

  // CSR by dst
  hipMemsetAsync(deg, 0, N_NODES * sizeof(int), stream);
  count_kernel<<<(N_EDGES + 255) / 256, 256, 0, stream>>>(edst, deg, N_EDGES);
  scan_kernel<<<1, 1024, 0, stream>>>(deg, off, N_NODES);
  hipMemsetAsync(deg, 0, N_NODES * sizeof(int), stream);
  fill_kernel<<<(N_EDGES + 255) / 256, 256, 0, stream>>>(esrc, edst, off, deg, ssrc, N_EDGES);

  dim3 gg1(HEADS * HID / GN, (N_NODES + GM - 1) / GM);
  int aggGrid = (N_NODES / 8) * 8;        // 10000 blocks: head = blk & 7
  int hmGrid = (N_NODES * 64 + 255) / 256;

  // ---- Layer 1 ----
  {
    int n4 = N_NODES * N_FEAT / 4;
    split_kernel<<<(n4 + 255) / 256, 256, 0, stream>>>(x, sAhi, sAlo, n4);
    int w4 = HEADS * HID * N_FEAT / 4;
    split_kernel<<<(w4 + 255) / 256, 256, 0, stream>>>(W1, sBhi, sBlo, w4);
    gemm_mfma_split<<<gg1, 256, 0, stream>>>(sAhi, sAlo, sBhi, sBlo, h, hb,
                                             N_NODES, N_FEAT, HEADS * HID);
  }
  scores_kernel<<<(N_NODES * HEADS + 3) / 4, 256, 0, stream>>>(h, a1, si, sj, N_NODES * HEADS);
  alpha_kernel<<<(N_NODES + 3) / 4, 256, 0, stream>>>(si, sj, off, ssrc, wbuf, invd, N_NODES);
  gat_aggregate2<<<aggGrid, 512, 0, stream>>>(hb, wbuf, invd, off, ssrc, aggbuf, N_NODES);
  headmean_kernel<<<hmGrid, 256, 0, stream>>>(aggbuf, emb1, N_NODES);

  // ---- Layer 2 ----
  {
    int n4 = N_NODES * HID / 4;
    split_kernel<<<(n4 + 255) / 256, 256, 0, stream>>>(emb1, sAhi, sAlo, n4);
    int w4 = HEADS * HID * HID / 4;
    split_kernel<<<(w4 + 255) / 256, 256, 0, stream>>>(W2, sBhi, sBlo, w4);
    gemm_mfma_split<<<gg1, 256, 0, stream>>>(sAhi, sAlo, sBhi, sBlo, h, hb,
                                             N_NODES, HID, HEADS * HID);
  }
  scores_kernel<<<(N_NODES * HEADS + 3) / 4, 256, 0, stream>>>(h, a2, si, sj, N_NODES * HEADS);
  alpha_kernel<<<(N_NODES + 3) / 4, 256, 0, stream>>>(si, sj, off, ssrc, wbuf, invd, N_NODES);
  gat_aggregate2<<<aggGrid, 512, 0, stream>>>(hb, wbuf, invd, off, ssrc, aggbuf, N_NODES);
  headmean_kernel<<<hmGrid, 256, 0, stream>>>(aggbuf, emb2, N_NODES);

  // ---- Pool + MLP head ----
  hipMemsetAsync(g, 0, HID * sizeof(float), stream);
  pool_kernel<<<100, 256, 0, stream>>>(emb2, g, N_NODES);
  mlp_kernel<<<1, 128, 0, stream>>>(g, ln_g, ln_b, Wl1, bl1, Wl2, bl2, Wl3, bl3,
                                    out, 1.0f / N_NODES);
}

// Round 5
// 381.231 us; speedup vs baseline: 1.2087x; 1.2087x over previous
//
#include <hip/hip_runtime.h>
#include <math.h>

#define N_NODES 10000
#define N_EDGES 160000
#define N_FEAT  512
#define HEADS   8
#define HID     128

typedef __attribute__((ext_vector_type(8))) short bf16x8;
typedef __attribute__((ext_vector_type(4))) float f32x4;

// ---------------------------------------------------------------------------
// fp32 <-> bf16 helpers
// ---------------------------------------------------------------------------
__device__ inline unsigned short f2bf_rne(float f) {
  unsigned int u = __float_as_uint(f);
  unsigned int r = u + 0x7fffu + ((u >> 16) & 1u);
  return (unsigned short)(r >> 16);
}
__device__ inline float bf2f(unsigned int b) {
  return __uint_as_float(b << 16);
}

__global__ __launch_bounds__(256)
void split_kernel(const float* __restrict__ in, unsigned short* __restrict__ hi,
                  unsigned short* __restrict__ lo, int n4) {
  int i = blockIdx.x * blockDim.x + threadIdx.x;
  if (i >= n4) return;
  float4 v = ((const float4*)in)[i];
  ushort4 h, l;
  h.x = f2bf_rne(v.x); l.x = f2bf_rne(v.x - bf2f(h.x));
  h.y = f2bf_rne(v.y); l.y = f2bf_rne(v.y - bf2f(h.y));
  h.z = f2bf_rne(v.z); l.z = f2bf_rne(v.z - bf2f(h.z));
  h.w = f2bf_rne(v.w); l.w = f2bf_rne(v.w - bf2f(h.w));
  ((ushort4*)hi)[i] = h;
  ((ushort4*)lo)[i] = l;
}

// ---------------------------------------------------------------------------
// Split-bf16 MFMA GEMM (3-term), 128x128 tile / 256 threads, one head per
// blockIdx.x. Epilogue: (a) hb[head][row][d] bf16 for the gather path,
// (b) fused attention scores si/sj from the fp32 accumulators (no fp32 C).
// ---------------------------------------------------------------------------
#define GM 128
#define GN 128
#define GK 32
#define AST 40

__global__ __launch_bounds__(256)
void gemm_mfma_split(const unsigned short* __restrict__ Ahi,
                     const unsigned short* __restrict__ Alo,
                     const unsigned short* __restrict__ Bhi,
                     const unsigned short* __restrict__ Blo,
                     const float* __restrict__ avec,
                     unsigned short* __restrict__ hb,
                     float* __restrict__ si, float* __restrict__ sj,
                     int M, int K) {
  __shared__ unsigned short sA[2][GM * AST];
  __shared__ unsigned short sB[2][GN * AST];
  __shared__ float rsi[128][2];
  __shared__ float rsj[128][2];
  int tid = threadIdx.x;
  int wave = tid >> 6, lane = tid & 63;
  int m0 = blockIdx.y * GM, n0 = blockIdx.x * GN;
  int wm = (wave & 1) * 64, wn = (wave >> 1) * 64;
  int r = lane & 15, q = lane >> 4;

  f32x4 acc[4][4] = {};

  for (int k0 = 0; k0 < K; k0 += GK) {
    #pragma unroll
    for (int t = 0; t < 2; ++t) {
      int idx = tid + t * 256;
      int row = idx >> 2, kq = idx & 3;
      int arow = m0 + row; if (arow >= M) arow = M - 1;
      size_t ga = (size_t)arow * K + k0 + kq * 8;
      int4 vhi = *(const int4*)&Ahi[ga];
      int4 vlo = *(const int4*)&Alo[ga];
      int la = row * AST + kq * 8;
      *(int4*)&sA[0][la] = vhi;
      *(int4*)&sA[1][la] = vlo;
      size_t gb = (size_t)(n0 + row) * K + k0 + kq * 8;
      int4 whi = *(const int4*)&Bhi[gb];
      int4 wlo = *(const int4*)&Blo[gb];
      *(int4*)&sB[0][la] = whi;
      *(int4*)&sB[1][la] = wlo;
    }
    __syncthreads();
    bf16x8 ah[4], al[4], bh[4], bl[4];
    #pragma unroll
    for (int i = 0; i < 4; ++i) {
      int ra = (wm + i * 16 + r) * AST + q * 8;
      ah[i] = *(const bf16x8*)&sA[0][ra];
      al[i] = *(const bf16x8*)&sA[1][ra];
      int rb = (wn + i * 16 + r) * AST + q * 8;
      bh[i] = *(const bf16x8*)&sB[0][rb];
      bl[i] = *(const bf16x8*)&sB[1][rb];
    }
    #pragma unroll
    for (int i = 0; i < 4; ++i)
      #pragma unroll
      for (int j = 0; j < 4; ++j) {
        acc[i][j] = __builtin_amdgcn_mfma_f32_16x16x32_bf16(ah[i], bh[j], acc[i][j], 0, 0, 0);
        acc[i][j] = __builtin_amdgcn_mfma_f32_16x16x32_bf16(ah[i], bl[j], acc[i][j], 0, 0, 0);
        acc[i][j] = __builtin_amdgcn_mfma_f32_16x16x32_bf16(al[i], bh[j], acc[i][j], 0, 0, 0);
      }
    __syncthreads();
  }

  // --- epilogue ---
  // C/D layout: col = lane&15 (=r), row = q*4 + reg  (within each 16x16 frag)
  int head = blockIdx.x;  // GN == HID
  const float* av = avec + (size_t)head * (2 * HID);
  float aiv[4], ajv[4];
  #pragma unroll
  for (int j = 0; j < 4; ++j) {
    int c = wn + j * 16 + r;
    aiv[j] = av[c];
    ajv[j] = av[HID + c];
  }
  #pragma unroll
  for (int i = 0; i < 4; ++i) {
    #pragma unroll
    for (int reg = 0; reg < 4; ++reg) {
      int row = m0 + wm + i * 16 + q * 4 + reg;
      float vsi = 0.f, vsj = 0.f;
      #pragma unroll
      for (int j = 0; j < 4; ++j) {
        float v = acc[i][j][reg];
        vsi = fmaf(v, aiv[j], vsi);
        vsj = fmaf(v, ajv[j], vsj);
        if (row < M)
          hb[((size_t)head * M + row) * HID + wn + j * 16 + r] = f2bf_rne(v);
      }
      #pragma unroll
      for (int o = 8; o >= 1; o >>= 1) {
        vsi += __shfl_xor(vsi, o);
        vsj += __shfl_xor(vsj, o);
      }
      if (r == 0) {
        int lrow = wm + i * 16 + q * 4 + reg;
        rsi[lrow][wave >> 1] = vsi;
        rsj[lrow][wave >> 1] = vsj;
      }
    }
  }
  __syncthreads();
  if (tid < 128) {
    int row = m0 + tid;
    if (row < M) {
      si[(size_t)row * HEADS + head] = rsi[tid][0] + rsi[tid][1];
      sj[(size_t)row * HEADS + head] = rsj[tid][0] + rsj[tid][1];
    }
  }
}

// ---------------------------------------------------------------------------
// CSR build
// ---------------------------------------------------------------------------
__global__ void count_kernel(const int* __restrict__ dst, int* __restrict__ deg, int E) {
  int e = blockIdx.x * blockDim.x + threadIdx.x;
  if (e < E) atomicAdd(&deg[dst[e]], 1);
}

__global__ __launch_bounds__(1024)
void scan_kernel(const int* __restrict__ deg, int* __restrict__ off, int N) {
  __shared__ int sums[1024];
  const int PER = 10;
  int tid = threadIdx.x;
  int base = tid * PER;
  int loc[PER];
  int run = 0;
  #pragma unroll
  for (int j = 0; j < PER; ++j) {
    int v = (base + j < N) ? deg[base + j] : 0;
    run += v;
    loc[j] = run;
  }
  sums[tid] = run;
  __syncthreads();
  for (int o = 1; o < 1024; o <<= 1) {
    int v = (tid >= o) ? sums[tid - o] : 0;
    __syncthreads();
    sums[tid] += v;
    __syncthreads();
  }
  int ex = sums[tid] - run;
  if (tid == 0) off[0] = 0;
  #pragma unroll
  for (int j = 0; j < PER; ++j)
    if (base + j < N) off[base + j + 1] = ex + loc[j];
}

__global__ void fill_kernel(const int* __restrict__ src, const int* __restrict__ dst,
                            const int* __restrict__ off, int* __restrict__ cursor,
                            int* __restrict__ ssrc, int E) {
  int e = blockIdx.x * blockDim.x + threadIdx.x;
  if (e < E) {
    int d = dst[e];
    int p = atomicAdd(&cursor[d], 1);
    ssrc[off[d] + p] = src[e];
  }
}

// ---------------------------------------------------------------------------
// Edge softmax weights: one wave per dst node. Lane = eidx*8 + head.
// ---------------------------------------------------------------------------
__global__ __launch_bounds__(256)
void alpha_kernel(const float* __restrict__ si, const float* __restrict__ sj,
                  const int* __restrict__ off, const int* __restrict__ ssrc,
                  float* __restrict__ w, float* __restrict__ invden, int N) {
  int wv = (blockIdx.x * blockDim.x + threadIdx.x) >> 6;
  if (wv >= N) return;
  int lane = threadIdx.x & 63;
  int eidx = lane >> 3, head = lane & 7;
  int begin = off[wv], end = off[wv + 1];
  float s_i = si[wv * HEADS + head];

  float m = -INFINITY;
  for (int k0 = begin; k0 < end; k0 += 8) {
    int k = k0 + eidx;
    if (k < end) {
      float e = s_i + sj[ssrc[k] * HEADS + head];
      e = e > 0.f ? e : 0.01f * e;
      m = fmaxf(m, e);
    }
  }
  m = fmaxf(m, __shfl_xor(m, 8));
  m = fmaxf(m, __shfl_xor(m, 16));
  m = fmaxf(m, __shfl_xor(m, 32));

  float sum = 0.f;
  for (int k0 = begin; k0 < end; k0 += 8) {
    int k = k0 + eidx;
    if (k < end) {
      float e = s_i + sj[ssrc[k] * HEADS + head];
      e = e > 0.f ? e : 0.01f * e;
      float wt = expf(e - m);
      w[(size_t)k * HEADS + head] = wt;
      sum += wt;
    }
  }
  sum += __shfl_xor(sum, 8);
  sum += __shfl_xor(sum, 16);
  sum += __shfl_xor(sum, 32);
  if (eidx == 0)
    invden[wv * HEADS + head] = sum > 0.f ? 1.0f / sum : 0.f;
}

// ---------------------------------------------------------------------------
// Aggregation v3: one wave per (dst, head); head = blockIdx.x & 7 (XCD/L2
// affinity). Wave = 4 groups x 16 lanes; each group handles one edge, each
// lane loads 16B (8 bf16 dims). 2x unrolled -> 8 edge-vectors in flight.
// Cross-group reduce via shfl_xor(16,32). aggbuf[head][n][d].
// ---------------------------------------------------------------------------
__global__ __launch_bounds__(512)
void gat_aggregate3(const unsigned short* __restrict__ hb,
                    const float* __restrict__ w, const float* __restrict__ invden,
                    const int* __restrict__ off, const int* __restrict__ ssrc,
                    float* __restrict__ aggbuf, int N) {
  int head = blockIdx.x & 7;
  int n = (blockIdx.x >> 3) * 8 + (threadIdx.x >> 6);
  if (n >= N) return;
  int lane = threadIdx.x & 63;
  int grp = lane >> 4;       // edge slot 0..3
  int l = lane & 15;         // dim group: dims l*8 .. l*8+7
  const unsigned short* hbase = hb + (size_t)head * N * HID;
  int begin = off[n], end = off[n + 1];

  float a0 = 0.f, a1 = 0.f, a2 = 0.f, a3 = 0.f;
  float a4 = 0.f, a5 = 0.f, a6 = 0.f, a7 = 0.f;

  for (int k0 = begin; k0 < end; k0 += 8) {
    int ka = k0 + grp;
    int kb = k0 + 4 + grp;
    int kka = ka < end ? ka : begin;
    int kkb = kb < end ? kb : begin;
    int sa = ssrc[kka];
    int sb = ssrc[kkb];
    float wa = w[(size_t)kka * HEADS + head];
    float wb = w[(size_t)kkb * HEADS + head];
    if (ka >= end) wa = 0.f;
    if (kb >= end) wb = 0.f;
    int4 pa = *(const int4*)&hbase[(size_t)sa * HID + l * 8];
    int4 pb = *(const int4*)&hbase[(size_t)sb * HID + l * 8];
    a0 = fmaf(wa, bf2f((unsigned)pa.x & 0xffffu), a0);
    a1 = fmaf(wa, __uint_as_float((unsigned)pa.x & 0xffff0000u), a1);
    a2 = fmaf(wa, bf2f((unsigned)pa.y & 0xffffu), a2);
    a3 = fmaf(wa, __uint_as_float((unsigned)pa.y & 0xffff0000u), a3);
    a4 = fmaf(wa, bf2f((unsigned)pa.z & 0xffffu), a4);
    a5 = fmaf(wa, __uint_as_float((unsigned)pa.z & 0xffff0000u), a5);
    a6 = fmaf(wa, bf2f((unsigned)pa.w & 0xffffu), a6);
    a7 = fmaf(wa, __uint_as_float((unsigned)pa.w & 0xffff0000u), a7);
    a0 = fmaf(wb, bf2f((unsigned)pb.x & 0xffffu), a0);
    a1 = fmaf(wb, __uint_as_float((unsigned)pb.x & 0xffff0000u), a1);
    a2 = fmaf(wb, bf2f((unsigned)pb.y & 0xffffu), a2);
    a3 = fmaf(wb, __uint_as_float((unsigned)pb.y & 0xffff0000u), a3);
    a4 = fmaf(wb, bf2f((unsigned)pb.z & 0xffffu), a4);
    a5 = fmaf(wb, __uint_as_float((unsigned)pb.z & 0xffff0000u), a5);
    a6 = fmaf(wb, bf2f((unsigned)pb.w & 0xffffu), a6);
    a7 = fmaf(wb, __uint_as_float((unsigned)pb.w & 0xffff0000u), a7);
  }
  // reduce across the 4 edge groups
  a0 += __shfl_xor(a0, 16); a1 += __shfl_xor(a1, 16);
  a2 += __shfl_xor(a2, 16); a3 += __shfl_xor(a3, 16);
  a4 += __shfl_xor(a4, 16); a5 += __shfl_xor(a5, 16);
  a6 += __shfl_xor(a6, 16); a7 += __shfl_xor(a7, 16);
  a0 += __shfl_xor(a0, 32); a1 += __shfl_xor(a1, 32);
  a2 += __shfl_xor(a2, 32); a3 += __shfl_xor(a3, 32);
  a4 += __shfl_xor(a4, 32); a5 += __shfl_xor(a5, 32);
  a6 += __shfl_xor(a6, 32); a7 += __shfl_xor(a7, 32);

  if (grp == 0) {
    float inv = invden[n * HEADS + head];
    float* dst = aggbuf + ((size_t)head * N + n) * HID + l * 8;
    *(float4*)dst = make_float4(a0 * inv, a1 * inv, a2 * inv, a3 * inv);
    *(float4*)(dst + 4) = make_float4(a4 * inv, a5 * inv, a6 * inv, a7 * inv);
  }
}

// ---------------------------------------------------------------------------
// Head mean + ELU: emb[n,d] = ELU(mean_h aggbuf[h][n][d])
// ---------------------------------------------------------------------------
__global__ __launch_bounds__(256)
void headmean_kernel(const float* __restrict__ aggbuf, float* __restrict__ emb, int N) {
  int i = blockIdx.x * blockDim.x + threadIdx.x;  // float2 index
  if (i >= N * 64) return;
  float sx = 0.f, sy = 0.f;
  #pragma unroll
  for (int hh = 0; hh < HEADS; ++hh) {
    float2 v = ((const float2*)aggbuf)[(size_t)hh * N * 64 + i];
    sx += v.x; sy += v.y;
  }
  sx *= (1.0f / HEADS); sy *= (1.0f / HEADS);
  float ox = sx > 0.f ? sx : (expf(sx) - 1.0f);
  float oy = sy > 0.f ? sy : (expf(sy) - 1.0f);
  ((float2*)emb)[i] = make_float2(ox, oy);
}

// ---------------------------------------------------------------------------
// Graph pooling
// ---------------------------------------------------------------------------
__global__ __launch_bounds__(256)
void pool_kernel(const float* __restrict__ emb, float* __restrict__ g, int N) {
  __shared__ float part[256];
  int d = threadIdx.x & 127;
  int half = threadIdx.x >> 7;
  int n0 = blockIdx.x * 100;
  float s = 0.f;
  for (int i = half; i < 100; i += 2) {
    int n = n0 + i;
    if (n < N) s += emb[(size_t)n * HID + d];
  }
  part[threadIdx.x] = s;
  __syncthreads();
  if (threadIdx.x < HID) atomicAdd(&g[d], part[threadIdx.x] + part[128 + threadIdx.x]);
}

// ---------------------------------------------------------------------------
// LayerNorm + MLP head
// ---------------------------------------------------------------------------
__global__ __launch_bounds__(128)
void mlp_kernel(const float* __restrict__ g, const float* __restrict__ ln_g,
                const float* __restrict__ ln_b, const float* __restrict__ Wl1,
                const float* __restrict__ bl1, const float* __restrict__ Wl2,
                const float* __restrict__ bl2, const float* __restrict__ Wl3,
                const float* __restrict__ bl3, float* __restrict__ out, float invN) {
  __shared__ float red[128];
  __shared__ float gn[128];
  __shared__ float x1[64];
  __shared__ float x2[16];
  int t = threadIdx.x;
  float gg = g[t] * invN;
  red[t] = gg;
  __syncthreads();
  for (int o = 64; o > 0; o >>= 1) {
    if (t < o) red[t] += red[t + o];
    __syncthreads();
  }
  float mu = red[0] * (1.0f / HID);
  __syncthreads();
  float dv = gg - mu;
  red[t] = dv * dv;
  __syncthreads();
  for (int o = 64; o > 0; o >>= 1) {
    if (t < o) red[t] += red[t + o];
    __syncthreads();
  }
  float var = red[0] * (1.0f / HID);
  gn[t] = dv / sqrtf(var + 1e-5f) * ln_g[t] + ln_b[t];
  __syncthreads();
  if (t < 64) {
    float s = bl1[t];
    for (int k = 0; k < 128; ++k) s += Wl1[t * 128 + k] * gn[k];
    x1[t] = s > 0.f ? s : 0.01f * s;
  }
  __syncthreads();
  if (t < 16) {
    float s = bl2[t];
    for (int k = 0; k < 64; ++k) s += Wl2[t * 64 + k] * x1[k];
    x2[t] = s > 0.f ? s : 0.01f * s;
  }
  __syncthreads();
  if (t < 16) {
    float s = bl3[t];
    for (int k = 0; k < 16; ++k) s += Wl3[t * 16 + k] * x2[k];
    out[t] = s > 0.f ? s : 0.f;
  }
}

// ---------------------------------------------------------------------------
extern "C" void kernel_launch(void* const* d_in, const int* in_sizes, int n_in,
                              void* d_out, int out_size, void* d_ws, size_t ws_size,
                              hipStream_t stream) {
  const float* x    = (const float*)d_in[0];
  const int*   esrc = (const int*)d_in[1];
  const int*   edst = (const int*)d_in[2];
  const float* W1   = (const float*)d_in[3];
  const float* a1   = (const float*)d_in[4];
  const float* W2   = (const float*)d_in[5];
  const float* a2   = (const float*)d_in[6];
  const float* ln_g = (const float*)d_in[7];
  const float* ln_b = (const float*)d_in[8];
  const float* Wl1  = (const float*)d_in[9];
  const float* bl1  = (const float*)d_in[10];
  const float* Wl2  = (const float*)d_in[11];
  const float* bl2  = (const float*)d_in[12];
  const float* Wl3  = (const float*)d_in[13];
  const float* bl3  = (const float*)d_in[14];
  float* out = (float*)d_out;

  float* ws   = (float*)d_ws;
  float* aggbuf = ws;                                   // 10,240,000 f (41 MB)
  float* si   = aggbuf + (size_t)N_NODES * HEADS * HID; // 80,000
  float* sj   = si + N_NODES * HEADS;                   // 80,000
  float* emb1 = sj + N_NODES * HEADS;                   // 1,280,000
  float* emb2 = emb1 + (size_t)N_NODES * HID;           // 1,280,000
  float* g    = emb2 + (size_t)N_NODES * HID;           // 128
  float* wbuf = g + 128;                                // 1,280,000
  float* invd = wbuf + (size_t)N_EDGES * HEADS;         // 80,000
  int*   deg  = (int*)(invd + N_NODES * HEADS);         // 10,000
  int*   off  = deg + N_NODES;                          // 10,001
  int*   ssrc = off + (N_NODES + 1);                    // 160,000
  unsigned short* sAhi = (unsigned short*)(ssrc + N_EDGES + 3);
  unsigned short* sAlo = sAhi + (size_t)N_NODES * N_FEAT;
  unsigned short* sBhi = sAlo + (size_t)N_NODES * N_FEAT;
  unsigned short* sBlo = sBhi + HEADS * HID * N_FEAT;
  unsigned short* hb   = sBlo + HEADS * HID * N_FEAT;   // 10,240,000 us (20.5 MB)

  // CSR by dst
  hipMemsetAsync(deg, 0, N_NODES * sizeof(int), stream);
  count_kernel<<<(N_EDGES + 255) / 256, 256, 0, stream>>>(edst, deg, N_EDGES);
  scan_kernel<<<1, 1024, 0, stream>>>(deg, off, N_NODES);
  hipMemsetAsync(deg, 0, N_NODES * sizeof(int), stream);
  fill_kernel<<<(N_EDGES + 255) / 256, 256, 0, stream>>>(esrc, edst, off, deg, ssrc, N_EDGES);

  dim3 gg1(HEADS * HID / GN, (N_NODES + GM - 1) / GM);
  int aggGrid = (N_NODES / 8) * 8;        // 10000 blocks: head = blk & 7
  int hmGrid = (N_NODES * 64 + 255) / 256;

  // ---- Layer 1 ----
  {
    int n4 = N_NODES * N_FEAT / 4;
    split_kernel<<<(n4 + 255) / 256, 256, 0, stream>>>(x, sAhi, sAlo, n4);
    int w4 = HEADS * HID * N_FEAT / 4;
    split_kernel<<<(w4 + 255) / 256, 256, 0, stream>>>(W1, sBhi, sBlo, w4);
    gemm_mfma_split<<<gg1, 256, 0, stream>>>(sAhi, sAlo, sBhi, sBlo, a1, hb,
                                             si, sj, N_NODES, N_FEAT);
  }
  alpha_kernel<<<(N_NODES + 3) / 4, 256, 0, stream>>>(si, sj, off, ssrc, wbuf, invd, N_NODES);
  gat_aggregate3<<<aggGrid, 512, 0, stream>>>(hb, wbuf, invd, off, ssrc, aggbuf, N_NODES);
  headmean_kernel<<<hmGrid, 256, 0, stream>>>(aggbuf, emb1, N_NODES);

  // ---- Layer 2 ----
  {
    int n4 = N_NODES * HID / 4;
    split_kernel<<<(n4 + 255) / 256, 256, 0, stream>>>(emb1, sAhi, sAlo, n4);
    int w4 = HEADS * HID * HID / 4;
    split_kernel<<<(w4 + 255) / 256, 256, 0, stream>>>(W2, sBhi, sBlo, w4);
    gemm_mfma_split<<<gg1, 256, 0, stream>>>(sAhi, sAlo, sBhi, sBlo, a2, hb,
                                             si, sj, N_NODES, HID);
  }
  alpha_kernel<<<(N_NODES + 3) / 4, 256, 0, stream>>>(si, sj, off, ssrc, wbuf, invd, N_NODES);
  gat_aggregate3<<<aggGrid, 512, 0, stream>>>(hb, wbuf, invd, off, ssrc, aggbuf, N_NODES);
  headmean_kernel<<<hmGrid, 256, 0, stream>>>(aggbuf, emb2, N_NODES);

  // ---- Pool + MLP head ----
  hipMemsetAsync(g, 0, HID * sizeof(float), stream);
  pool_kernel<<<100, 256, 0, stream>>>(emb2, g, N_NODES);
  mlp_kernel<<<1, 128, 0, stream>>>(g, ln_g, ln_b, Wl1, bl1, Wl2, bl2, Wl3, bl3,
                                    out, 1.0f / N_NODES);
}

// Round 6
// 363.536 us; speedup vs baseline: 1.2675x; 1.0487x over previous
//
#include <hip/hip_runtime.h>
#include <math.h>

#define N_NODES 10000
#define N_EDGES 160000
#define N_FEAT  512
#define HEADS   8
#define HID     128

typedef __attribute__((ext_vector_type(8))) short bf16x8;
typedef __attribute__((ext_vector_type(4))) float f32x4;

// ---------------------------------------------------------------------------
// fp32 <-> bf16 helpers
// ---------------------------------------------------------------------------
__device__ inline unsigned short f2bf_rne(float f) {
  unsigned int u = __float_as_uint(f);
  unsigned int r = u + 0x7fffu + ((u >> 16) & 1u);
  return (unsigned short)(r >> 16);
}
__device__ inline float bf2f(unsigned int b) {
  return __uint_as_float(b << 16);
}

__global__ __launch_bounds__(256)
void split_kernel(const float* __restrict__ in, unsigned short* __restrict__ hi,
                  unsigned short* __restrict__ lo, int n4) {
  int i = blockIdx.x * blockDim.x + threadIdx.x;
  if (i >= n4) return;
  float4 v = ((const float4*)in)[i];
  ushort4 h, l;
  h.x = f2bf_rne(v.x); l.x = f2bf_rne(v.x - bf2f(h.x));
  h.y = f2bf_rne(v.y); l.y = f2bf_rne(v.y - bf2f(h.y));
  h.z = f2bf_rne(v.z); l.z = f2bf_rne(v.z - bf2f(h.z));
  h.w = f2bf_rne(v.w); l.w = f2bf_rne(v.w - bf2f(h.w));
  ((ushort4*)hi)[i] = h;
  ((ushort4*)lo)[i] = l;
}

// ---------------------------------------------------------------------------
// Split-bf16 MFMA GEMM v2: 64x128 tile (one full head in N), 256 threads.
// 1-D grid of 1280 blocks, swizzled so blk%8 == mtile%8: all 8 heads of one
// m-tile land on the same XCD (L2 A-reuse); 160 padded m-tiles x 8 heads.
// Wave w covers cols [w*32, w*32+32) for all 64 rows: 4x2 frags of 16x16x32.
// Epilogue: fused si/sj scores from fp32 accumulators + bf16 hb write.
// ---------------------------------------------------------------------------
#define TM2 64
#define GK2 32
#define AST 40

__global__ __launch_bounds__(256)
void gemm_mfma_split2(const unsigned short* __restrict__ Ahi,
                      const unsigned short* __restrict__ Alo,
                      const unsigned short* __restrict__ Bhi,
                      const unsigned short* __restrict__ Blo,
                      const float* __restrict__ avec,
                      unsigned short* __restrict__ hb,
                      float* __restrict__ si, float* __restrict__ sj,
                      int M, int K) {
  __shared__ unsigned short sA[2][TM2 * AST];   // 10240 B
  __shared__ unsigned short sB[2][HID * AST];   // 20480 B
  __shared__ float rsi[TM2][4];                 // 1024 B
  __shared__ float rsj[TM2][4];                 // 1024 B

  int tid = threadIdx.x;
  int wave = tid >> 6, lane = tid & 63;
  int r = lane & 15, q = lane >> 4;

  int blk = blockIdx.x;
  int rr = blk & 7;
  int g  = blk >> 3;
  int head = g & 7;
  int mtile = (g >> 3) * 8 + rr;   // blk%8 == mtile%8 -> XCD affinity by m-tile
  int m0 = mtile * TM2;
  int wn = wave * 32;

  const unsigned short* Bh = Bhi + (size_t)head * HID * K;
  const unsigned short* Bl = Blo + (size_t)head * HID * K;

  f32x4 acc[4][2] = {};

  for (int k0 = 0; k0 < K; k0 += GK2) {
    // stage A: 64 rows x 32 cols (hi+lo), 1 int4 each per thread
    {
      int row = tid >> 2, kq = tid & 3;
      int arow = m0 + row; if (arow >= M) arow = M - 1;
      size_t ga = (size_t)arow * K + k0 + kq * 8;
      int la = row * AST + kq * 8;
      *(int4*)&sA[0][la] = *(const int4*)&Ahi[ga];
      *(int4*)&sA[1][la] = *(const int4*)&Alo[ga];
    }
    // stage B: 128 rows x 32 cols (hi+lo), 2 int4 each per thread
    #pragma unroll
    for (int t = 0; t < 2; ++t) {
      int idx = tid + t * 256;
      int row = idx >> 2, kq = idx & 3;
      size_t gb = (size_t)row * K + k0 + kq * 8;
      int lb = row * AST + kq * 8;
      *(int4*)&sB[0][lb] = *(const int4*)&Bh[gb];
      *(int4*)&sB[1][lb] = *(const int4*)&Bl[gb];
    }
    __syncthreads();
    bf16x8 ah[4], al[4], bh[2], bl[2];
    #pragma unroll
    for (int i = 0; i < 4; ++i) {
      int ra = (i * 16 + r) * AST + q * 8;
      ah[i] = *(const bf16x8*)&sA[0][ra];
      al[i] = *(const bf16x8*)&sA[1][ra];
    }
    #pragma unroll
    for (int j = 0; j < 2; ++j) {
      int rb = (wn + j * 16 + r) * AST + q * 8;
      bh[j] = *(const bf16x8*)&sB[0][rb];
      bl[j] = *(const bf16x8*)&sB[1][rb];
    }
    #pragma unroll
    for (int i = 0; i < 4; ++i)
      #pragma unroll
      for (int j = 0; j < 2; ++j) {
        acc[i][j] = __builtin_amdgcn_mfma_f32_16x16x32_bf16(ah[i], bh[j], acc[i][j], 0, 0, 0);
        acc[i][j] = __builtin_amdgcn_mfma_f32_16x16x32_bf16(ah[i], bl[j], acc[i][j], 0, 0, 0);
        acc[i][j] = __builtin_amdgcn_mfma_f32_16x16x32_bf16(al[i], bh[j], acc[i][j], 0, 0, 0);
      }
    __syncthreads();
  }

  // --- epilogue: C/D layout col = r, row = q*4 + reg (per 16x16 frag) ---
  const float* av = avec + (size_t)head * (2 * HID);
  float aiv[2], ajv[2];
  #pragma unroll
  for (int j = 0; j < 2; ++j) {
    int c = wn + j * 16 + r;
    aiv[j] = av[c];
    ajv[j] = av[HID + c];
  }
  #pragma unroll
  for (int i = 0; i < 4; ++i) {
    #pragma unroll
    for (int reg = 0; reg < 4; ++reg) {
      int lrow = i * 16 + q * 4 + reg;
      int row = m0 + lrow;
      float vsi = 0.f, vsj = 0.f;
      #pragma unroll
      for (int j = 0; j < 2; ++j) {
        float v = acc[i][j][reg];
        vsi = fmaf(v, aiv[j], vsi);
        vsj = fmaf(v, ajv[j], vsj);
        if (row < M)
          hb[((size_t)head * M + row) * HID + wn + j * 16 + r] = f2bf_rne(v);
      }
      #pragma unroll
      for (int o = 8; o >= 1; o >>= 1) {
        vsi += __shfl_xor(vsi, o);
        vsj += __shfl_xor(vsj, o);
      }
      if (r == 0) {
        rsi[lrow][wave] = vsi;
        rsj[lrow][wave] = vsj;
      }
    }
  }
  __syncthreads();
  if (tid < TM2) {
    int row = m0 + tid;
    if (row < M) {
      si[(size_t)row * HEADS + head] = rsi[tid][0] + rsi[tid][1] + rsi[tid][2] + rsi[tid][3];
      sj[(size_t)row * HEADS + head] = rsj[tid][0] + rsj[tid][1] + rsj[tid][2] + rsj[tid][3];
    }
  }
}

// ---------------------------------------------------------------------------
// CSR build
// ---------------------------------------------------------------------------
__global__ void count_kernel(const int* __restrict__ dst, int* __restrict__ deg, int E) {
  int e = blockIdx.x * blockDim.x + threadIdx.x;
  if (e < E) atomicAdd(&deg[dst[e]], 1);
}

__global__ __launch_bounds__(1024)
void scan_kernel(const int* __restrict__ deg, int* __restrict__ off, int N) {
  __shared__ int sums[1024];
  const int PER = 10;
  int tid = threadIdx.x;
  int base = tid * PER;
  int loc[PER];
  int run = 0;
  #pragma unroll
  for (int j = 0; j < PER; ++j) {
    int v = (base + j < N) ? deg[base + j] : 0;
    run += v;
    loc[j] = run;
  }
  sums[tid] = run;
  __syncthreads();
  for (int o = 1; o < 1024; o <<= 1) {
    int v = (tid >= o) ? sums[tid - o] : 0;
    __syncthreads();
    sums[tid] += v;
    __syncthreads();
  }
  int ex = sums[tid] - run;
  if (tid == 0) off[0] = 0;
  #pragma unroll
  for (int j = 0; j < PER; ++j)
    if (base + j < N) off[base + j + 1] = ex + loc[j];
}

__global__ void fill_kernel(const int* __restrict__ src, const int* __restrict__ dst,
                            const int* __restrict__ off, int* __restrict__ cursor,
                            int* __restrict__ ssrc, int E) {
  int e = blockIdx.x * blockDim.x + threadIdx.x;
  if (e < E) {
    int d = dst[e];
    int p = atomicAdd(&cursor[d], 1);
    ssrc[off[d] + p] = src[e];
  }
}

// ---------------------------------------------------------------------------
// Edge softmax weights: one wave per dst node. Lane = eidx*8 + head.
// ---------------------------------------------------------------------------
__global__ __launch_bounds__(256)
void alpha_kernel(const float* __restrict__ si, const float* __restrict__ sj,
                  const int* __restrict__ off, const int* __restrict__ ssrc,
                  float* __restrict__ w, float* __restrict__ invden, int N) {
  int wv = (blockIdx.x * blockDim.x + threadIdx.x) >> 6;
  if (wv >= N) return;
  int lane = threadIdx.x & 63;
  int eidx = lane >> 3, head = lane & 7;
  int begin = off[wv], end = off[wv + 1];
  float s_i = si[wv * HEADS + head];

  float m = -INFINITY;
  for (int k0 = begin; k0 < end; k0 += 8) {
    int k = k0 + eidx;
    if (k < end) {
      float e = s_i + sj[ssrc[k] * HEADS + head];
      e = e > 0.f ? e : 0.01f * e;
      m = fmaxf(m, e);
    }
  }
  m = fmaxf(m, __shfl_xor(m, 8));
  m = fmaxf(m, __shfl_xor(m, 16));
  m = fmaxf(m, __shfl_xor(m, 32));

  float sum = 0.f;
  for (int k0 = begin; k0 < end; k0 += 8) {
    int k = k0 + eidx;
    if (k < end) {
      float e = s_i + sj[ssrc[k] * HEADS + head];
      e = e > 0.f ? e : 0.01f * e;
      float wt = expf(e - m);
      w[(size_t)k * HEADS + head] = wt;
      sum += wt;
    }
  }
  sum += __shfl_xor(sum, 8);
  sum += __shfl_xor(sum, 16);
  sum += __shfl_xor(sum, 32);
  if (eidx == 0)
    invden[wv * HEADS + head] = sum > 0.f ? 1.0f / sum : 0.f;
}

// ---------------------------------------------------------------------------
// Aggregation v3: one wave per (dst, head); head = blockIdx.x & 7 (XCD/L2
// affinity). Wave = 4 groups x 16 lanes; each group one edge, each lane 16B.
// ---------------------------------------------------------------------------
__global__ __launch_bounds__(512)
void gat_aggregate3(const unsigned short* __restrict__ hb,
                    const float* __restrict__ w, const float* __restrict__ invden,
                    const int* __restrict__ off, const int* __restrict__ ssrc,
                    float* __restrict__ aggbuf, int N) {
  int head = blockIdx.x & 7;
  int n = (blockIdx.x >> 3) * 8 + (threadIdx.x >> 6);
  if (n >= N) return;
  int lane = threadIdx.x & 63;
  int grp = lane >> 4;
  int l = lane & 15;
  const unsigned short* hbase = hb + (size_t)head * N * HID;
  int begin = off[n], end = off[n + 1];

  float a0 = 0.f, a1 = 0.f, a2 = 0.f, a3 = 0.f;
  float a4 = 0.f, a5 = 0.f, a6 = 0.f, a7 = 0.f;

  for (int k0 = begin; k0 < end; k0 += 8) {
    int ka = k0 + grp;
    int kb = k0 + 4 + grp;
    int kka = ka < end ? ka : begin;
    int kkb = kb < end ? kb : begin;
    int sa = ssrc[kka];
    int sb = ssrc[kkb];
    float wa = w[(size_t)kka * HEADS + head];
    float wb = w[(size_t)kkb * HEADS + head];
    if (ka >= end) wa = 0.f;
    if (kb >= end) wb = 0.f;
    int4 pa = *(const int4*)&hbase[(size_t)sa * HID + l * 8];
    int4 pb = *(const int4*)&hbase[(size_t)sb * HID + l * 8];
    a0 = fmaf(wa, bf2f((unsigned)pa.x & 0xffffu), a0);
    a1 = fmaf(wa, __uint_as_float((unsigned)pa.x & 0xffff0000u), a1);
    a2 = fmaf(wa, bf2f((unsigned)pa.y & 0xffffu), a2);
    a3 = fmaf(wa, __uint_as_float((unsigned)pa.y & 0xffff0000u), a3);
    a4 = fmaf(wa, bf2f((unsigned)pa.z & 0xffffu), a4);
    a5 = fmaf(wa, __uint_as_float((unsigned)pa.z & 0xffff0000u), a5);
    a6 = fmaf(wa, bf2f((unsigned)pa.w & 0xffffu), a6);
    a7 = fmaf(wa, __uint_as_float((unsigned)pa.w & 0xffff0000u), a7);
    a0 = fmaf(wb, bf2f((unsigned)pb.x & 0xffffu), a0);
    a1 = fmaf(wb, __uint_as_float((unsigned)pb.x & 0xffff0000u), a1);
    a2 = fmaf(wb, bf2f((unsigned)pb.y & 0xffffu), a2);
    a3 = fmaf(wb, __uint_as_float((unsigned)pb.y & 0xffff0000u), a3);
    a4 = fmaf(wb, bf2f((unsigned)pb.z & 0xffffu), a4);
    a5 = fmaf(wb, __uint_as_float((unsigned)pb.z & 0xffff0000u), a5);
    a6 = fmaf(wb, bf2f((unsigned)pb.w & 0xffffu), a6);
    a7 = fmaf(wb, __uint_as_float((unsigned)pb.w & 0xffff0000u), a7);
  }
  a0 += __shfl_xor(a0, 16); a1 += __shfl_xor(a1, 16);
  a2 += __shfl_xor(a2, 16); a3 += __shfl_xor(a3, 16);
  a4 += __shfl_xor(a4, 16); a5 += __shfl_xor(a5, 16);
  a6 += __shfl_xor(a6, 16); a7 += __shfl_xor(a7, 16);
  a0 += __shfl_xor(a0, 32); a1 += __shfl_xor(a1, 32);
  a2 += __shfl_xor(a2, 32); a3 += __shfl_xor(a3, 32);
  a4 += __shfl_xor(a4, 32); a5 += __shfl_xor(a5, 32);
  a6 += __shfl_xor(a6, 32); a7 += __shfl_xor(a7, 32);

  if (grp == 0) {
    float inv = invden[n * HEADS + head];
    float* dst = aggbuf + ((size_t)head * N + n) * HID + l * 8;
    *(float4*)dst = make_float4(a0 * inv, a1 * inv, a2 * inv, a3 * inv);
    *(float4*)(dst + 4) = make_float4(a4 * inv, a5 * inv, a6 * inv, a7 * inv);
  }
}

// ---------------------------------------------------------------------------
// Head mean + ELU
// ---------------------------------------------------------------------------
__global__ __launch_bounds__(256)
void headmean_kernel(const float* __restrict__ aggbuf, float* __restrict__ emb, int N) {
  int i = blockIdx.x * blockDim.x + threadIdx.x;
  if (i >= N * 64) return;
  float sx = 0.f, sy = 0.f;
  #pragma unroll
  for (int hh = 0; hh < HEADS; ++hh) {
    float2 v = ((const float2*)aggbuf)[(size_t)hh * N * 64 + i];
    sx += v.x; sy += v.y;
  }
  sx *= (1.0f / HEADS); sy *= (1.0f / HEADS);
  float ox = sx > 0.f ? sx : (expf(sx) - 1.0f);
  float oy = sy > 0.f ? sy : (expf(sy) - 1.0f);
  ((float2*)emb)[i] = make_float2(ox, oy);
}

// ---------------------------------------------------------------------------
// Graph pooling
// ---------------------------------------------------------------------------
__global__ __launch_bounds__(256)
void pool_kernel(const float* __restrict__ emb, float* __restrict__ g, int N) {
  __shared__ float part[256];
  int d = threadIdx.x & 127;
  int half = threadIdx.x >> 7;
  int n0 = blockIdx.x * 100;
  float s = 0.f;
  for (int i = half; i < 100; i += 2) {
    int n = n0 + i;
    if (n < N) s += emb[(size_t)n * HID + d];
  }
  part[threadIdx.x] = s;
  __syncthreads();
  if (threadIdx.x < HID) atomicAdd(&g[d], part[threadIdx.x] + part[128 + threadIdx.x]);
}

// ---------------------------------------------------------------------------
// LayerNorm + MLP head
// ---------------------------------------------------------------------------
__global__ __launch_bounds__(128)
void mlp_kernel(const float* __restrict__ g, const float* __restrict__ ln_g,
                const float* __restrict__ ln_b, const float* __restrict__ Wl1,
                const float* __restrict__ bl1, const float* __restrict__ Wl2,
                const float* __restrict__ bl2, const float* __restrict__ Wl3,
                const float* __restrict__ bl3, float* __restrict__ out, float invN) {
  __shared__ float red[128];
  __shared__ float gn[128];
  __shared__ float x1[64];
  __shared__ float x2[16];
  int t = threadIdx.x;
  float gg = g[t] * invN;
  red[t] = gg;
  __syncthreads();
  for (int o = 64; o > 0; o >>= 1) {
    if (t < o) red[t] += red[t + o];
    __syncthreads();
  }
  float mu = red[0] * (1.0f / HID);
  __syncthreads();
  float dv = gg - mu;
  red[t] = dv * dv;
  __syncthreads();
  for (int o = 64; o > 0; o >>= 1) {
    if (t < o) red[t] += red[t + o];
    __syncthreads();
  }
  float var = red[0] * (1.0f / HID);
  gn[t] = dv / sqrtf(var + 1e-5f) * ln_g[t] + ln_b[t];
  __syncthreads();
  if (t < 64) {
    float s = bl1[t];
    for (int k = 0; k < 128; ++k) s += Wl1[t * 128 + k] * gn[k];
    x1[t] = s > 0.f ? s : 0.01f * s;
  }
  __syncthreads();
  if (t < 16) {
    float s = bl2[t];
    for (int k = 0; k < 64; ++k) s += Wl2[t * 64 + k] * x1[k];
    x2[t] = s > 0.f ? s : 0.01f * s;
  }
  __syncthreads();
  if (t < 16) {
    float s = bl3[t];
    for (int k = 0; k < 16; ++k) s += Wl3[t * 16 + k] * x2[k];
    out[t] = s > 0.f ? s : 0.f;
  }
}

// ---------------------------------------------------------------------------
extern "C" void kernel_launch(void* const* d_in, const int* in_sizes, int n_in,
                              void* d_out, int out_size, void* d_ws, size_t ws_size,
                              hipStream_t stream) {
  const float* x    = (const float*)d_in[0];
  const int*   esrc = (const int*)d_in[1];
  const int*   edst = (const int*)d_in[2];
  const float* W1   = (const float*)d_in[3];
  const float* a1   = (const float*)d_in[4];
  const float* W2   = (const float*)d_in[5];
  const float* a2   = (const float*)d_in[6];
  const float* ln_g = (const float*)d_in[7];
  const float* ln_b = (const float*)d_in[8];
  const float* Wl1  = (const float*)d_in[9];
  const float* bl1  = (const float*)d_in[10];
  const float* Wl2  = (const float*)d_in[11];
  const float* bl2  = (const float*)d_in[12];
  const float* Wl3  = (const float*)d_in[13];
  const float* bl3  = (const float*)d_in[14];
  float* out = (float*)d_out;

  float* ws   = (float*)d_ws;
  float* aggbuf = ws;                                   // 10,240,000 f (41 MB)
  float* si   = aggbuf + (size_t)N_NODES * HEADS * HID; // 80,000
  float* sj   = si + N_NODES * HEADS;                   // 80,000
  float* emb1 = sj + N_NODES * HEADS;                   // 1,280,000
  float* emb2 = emb1 + (size_t)N_NODES * HID;           // 1,280,000
  float* g    = emb2 + (size_t)N_NODES * HID;           // 128
  float* wbuf = g + 128;                                // 1,280,000
  float* invd = wbuf + (size_t)N_EDGES * HEADS;         // 80,000
  int*   deg  = (int*)(invd + N_NODES * HEADS);         // 10,000
  int*   off  = deg + N_NODES;                          // 10,001
  int*   ssrc = off + (N_NODES + 1);                    // 160,000
  unsigned short* sAhi = (unsigned short*)(ssrc + N_EDGES + 3);
  unsigned short* sAlo = sAhi + (size_t)N_NODES * N_FEAT;
  unsigned short* sBhi = sAlo + (size_t)N_NODES * N_FEAT;
  unsigned short* sBlo = sBhi + HEADS * HID * N_FEAT;
  unsigned short* hb   = sBlo + HEADS * HID * N_FEAT;   // 20.5 MB

  // CSR by dst
  hipMemsetAsync(deg, 0, N_NODES * sizeof(int), stream);
  count_kernel<<<(N_EDGES + 255) / 256, 256, 0, stream>>>(edst, deg, N_EDGES);
  scan_kernel<<<1, 1024, 0, stream>>>(deg, off, N_NODES);
  hipMemsetAsync(deg, 0, N_NODES * sizeof(int), stream);
  fill_kernel<<<(N_EDGES + 255) / 256, 256, 0, stream>>>(esrc, edst, off, deg, ssrc, N_EDGES);

  int nMTiles = (N_NODES + TM2 - 1) / TM2;        // 157
  int nMTilesPad = ((nMTiles + 7) / 8) * 8;       // 160
  int gemmGrid = nMTilesPad * HEADS;              // 1280
  int aggGrid = (N_NODES / 8) * 8;
  int hmGrid = (N_NODES * 64 + 255) / 256;

  // ---- Layer 1 ----
  {
    int n4 = N_NODES * N_FEAT / 4;
    split_kernel<<<(n4 + 255) / 256, 256, 0, stream>>>(x, sAhi, sAlo, n4);
    int w4 = HEADS * HID * N_FEAT / 4;
    split_kernel<<<(w4 + 255) / 256, 256, 0, stream>>>(W1, sBhi, sBlo, w4);
    gemm_mfma_split2<<<gemmGrid, 256, 0, stream>>>(sAhi, sAlo, sBhi, sBlo, a1, hb,
                                                   si, sj, N_NODES, N_FEAT);
  }
  alpha_kernel<<<(N_NODES + 3) / 4, 256, 0, stream>>>(si, sj, off, ssrc, wbuf, invd, N_NODES);
  gat_aggregate3<<<aggGrid, 512, 0, stream>>>(hb, wbuf, invd, off, ssrc, aggbuf, N_NODES);
  headmean_kernel<<<hmGrid, 256, 0, stream>>>(aggbuf, emb1, N_NODES);

  // ---- Layer 2 ----
  {
    int n4 = N_NODES * HID / 4;
    split_kernel<<<(n4 + 255) / 256, 256, 0, stream>>>(emb1, sAhi, sAlo, n4);
    int w4 = HEADS * HID * HID / 4;
    split_kernel<<<(w4 + 255) / 256, 256, 0, stream>>>(W2, sBhi, sBlo, w4);
    gemm_mfma_split2<<<gemmGrid, 256, 0, stream>>>(sAhi, sAlo, sBhi, sBlo, a2, hb,
                                                   si, sj, N_NODES, HID);
  }
  alpha_kernel<<<(N_NODES + 3) / 4, 256, 0, stream>>>(si, sj, off, ssrc, wbuf, invd, N_NODES);
  gat_aggregate3<<<aggGrid, 512, 0, stream>>>(hb, wbuf, invd, off, ssrc, aggbuf, N_NODES);
  headmean_kernel<<<hmGrid, 256, 0, stream>>>(aggbuf, emb2, N_NODES);

  // ---- Pool + MLP head ----
  hipMemsetAsync(g, 0, HID * sizeof(float), stream);
  pool_kernel<<<100, 256, 0, stream>>>(emb2, g, N_NODES);
  mlp_kernel<<<1, 128, 0, stream>>>(g, ln_g, ln_b, Wl1, bl1, Wl2, bl2, Wl3, bl3,
                                    out, 1.0f / N_NODES);
}

// Round 7
// 354.450 us; speedup vs baseline: 1.3000x; 1.0256x over previous
//
#include <hip/hip_runtime.h>
#include <math.h>

#define N_NODES 10000
#define N_EDGES 160000
#define N_FEAT  512
#define HEADS   8
#define HID     128

typedef __attribute__((ext_vector_type(8))) short bf16x8;
typedef __attribute__((ext_vector_type(4))) float f32x4;

// ---------------------------------------------------------------------------
// fp32 <-> bf16 helpers
// ---------------------------------------------------------------------------
__device__ inline unsigned short f2bf_rne(float f) {
  unsigned int u = __float_as_uint(f);
  unsigned int r = u + 0x7fffu + ((u >> 16) & 1u);
  return (unsigned short)(r >> 16);
}
__device__ inline float bf2f(unsigned int b) {
  return __uint_as_float(b << 16);
}

__global__ __launch_bounds__(256)
void split_kernel(const float* __restrict__ in, unsigned short* __restrict__ hi,
                  unsigned short* __restrict__ lo, int n4) {
  int i = blockIdx.x * blockDim.x + threadIdx.x;
  if (i >= n4) return;
  float4 v = ((const float4*)in)[i];
  ushort4 h, l;
  h.x = f2bf_rne(v.x); l.x = f2bf_rne(v.x - bf2f(h.x));
  h.y = f2bf_rne(v.y); l.y = f2bf_rne(v.y - bf2f(h.y));
  h.z = f2bf_rne(v.z); l.z = f2bf_rne(v.z - bf2f(h.z));
  h.w = f2bf_rne(v.w); l.w = f2bf_rne(v.w - bf2f(h.w));
  ((ushort4*)hi)[i] = h;
  ((ushort4*)lo)[i] = l;
}

// ---------------------------------------------------------------------------
// Split-bf16 MFMA GEMM v3: 128x128 block tile (full head in N), 256 threads,
// 4 waves in 2x2, each wave a 64x64 sub-tile (4x4 frags of 16x16x32, 3-term
// split = 48 MFMAs/wave/K-iter vs 16 LDS b128 reads -> 3:1 intensity).
// 1-D grid of 640 blocks swizzled so blk%8 == mtile%8 (XCD L2 A-reuse).
// Epilogue: fused si/sj scores + bf16 hb (head-major) write; no fp32 C.
// ---------------------------------------------------------------------------
#define TM3 128
#define BK3 32
#define AST 40

__global__ __launch_bounds__(256, 3)
void gemm_mfma_split3(const unsigned short* __restrict__ Ahi,
                      const unsigned short* __restrict__ Alo,
                      const unsigned short* __restrict__ Bhi,
                      const unsigned short* __restrict__ Blo,
                      const float* __restrict__ avec,
                      unsigned short* __restrict__ hb,
                      float* __restrict__ si, float* __restrict__ sj,
                      int M, int K) {
  __shared__ unsigned short sA[2][TM3 * AST];   // 20480 B
  __shared__ unsigned short sB[2][HID * AST];   // 20480 B
  __shared__ float rsi[TM3][2];
  __shared__ float rsj[TM3][2];

  int tid = threadIdx.x;
  int wave = tid >> 6, lane = tid & 63;
  int r = lane & 15, q = lane >> 4;

  int blk = blockIdx.x;
  int rr = blk & 7;
  int g  = blk >> 3;
  int head = g & 7;
  int mtile = (g >> 3) * 8 + rr;   // blk%8 == mtile%8 -> XCD affinity by m-tile
  int m0 = mtile * TM3;
  int wm = (wave & 1) * 64;
  int wn = (wave >> 1) * 64;

  const unsigned short* Bh = Bhi + (size_t)head * HID * K;
  const unsigned short* Bl = Blo + (size_t)head * HID * K;

  f32x4 acc[4][4] = {};

  int srow = tid >> 1, shalf = tid & 1;   // staging: 128 rows, 2x32B halves
  for (int k0 = 0; k0 < K; k0 += BK3) {
    {
      int arow = m0 + srow; if (arow >= M) arow = M - 1;
      size_t ga = (size_t)arow * K + k0 + shalf * 16;
      int la = srow * AST + shalf * 16;
      *(int4*)&sA[0][la]     = *(const int4*)&Ahi[ga];
      *(int4*)&sA[0][la + 8] = *(const int4*)&Ahi[ga + 8];
      *(int4*)&sA[1][la]     = *(const int4*)&Alo[ga];
      *(int4*)&sA[1][la + 8] = *(const int4*)&Alo[ga + 8];
      size_t gb = (size_t)srow * K + k0 + shalf * 16;
      *(int4*)&sB[0][la]     = *(const int4*)&Bh[gb];
      *(int4*)&sB[0][la + 8] = *(const int4*)&Bh[gb + 8];
      *(int4*)&sB[1][la]     = *(const int4*)&Bl[gb];
      *(int4*)&sB[1][la + 8] = *(const int4*)&Bl[gb + 8];
    }
    __syncthreads();
    bf16x8 ah[4], al[4], bh[4], bl[4];
    #pragma unroll
    for (int i = 0; i < 4; ++i) {
      int ra = (wm + i * 16 + r) * AST + q * 8;
      ah[i] = *(const bf16x8*)&sA[0][ra];
      al[i] = *(const bf16x8*)&sA[1][ra];
    }
    #pragma unroll
    for (int j = 0; j < 4; ++j) {
      int rb = (wn + j * 16 + r) * AST + q * 8;
      bh[j] = *(const bf16x8*)&sB[0][rb];
      bl[j] = *(const bf16x8*)&sB[1][rb];
    }
    #pragma unroll
    for (int i = 0; i < 4; ++i)
      #pragma unroll
      for (int j = 0; j < 4; ++j) {
        acc[i][j] = __builtin_amdgcn_mfma_f32_16x16x32_bf16(ah[i], bh[j], acc[i][j], 0, 0, 0);
        acc[i][j] = __builtin_amdgcn_mfma_f32_16x16x32_bf16(ah[i], bl[j], acc[i][j], 0, 0, 0);
        acc[i][j] = __builtin_amdgcn_mfma_f32_16x16x32_bf16(al[i], bh[j], acc[i][j], 0, 0, 0);
      }
    __syncthreads();
  }

  // --- epilogue: C/D layout col = r, row = q*4 + reg (per 16x16 frag) ---
  const float* av = avec + (size_t)head * (2 * HID);
  float aiv[4], ajv[4];
  #pragma unroll
  for (int j = 0; j < 4; ++j) {
    int c = wn + j * 16 + r;
    aiv[j] = av[c];
    ajv[j] = av[HID + c];
  }
  #pragma unroll
  for (int i = 0; i < 4; ++i) {
    #pragma unroll
    for (int reg = 0; reg < 4; ++reg) {
      int lrow = wm + i * 16 + q * 4 + reg;
      int row = m0 + lrow;
      float vsi = 0.f, vsj = 0.f;
      #pragma unroll
      for (int j = 0; j < 4; ++j) {
        float v = acc[i][j][reg];
        vsi = fmaf(v, aiv[j], vsi);
        vsj = fmaf(v, ajv[j], vsj);
        if (row < M)
          hb[((size_t)head * M + row) * HID + wn + j * 16 + r] = f2bf_rne(v);
      }
      #pragma unroll
      for (int o = 8; o >= 1; o >>= 1) {
        vsi += __shfl_xor(vsi, o);
        vsj += __shfl_xor(vsj, o);
      }
      if (r == 0) {
        rsi[lrow][wn >> 6] = vsi;
        rsj[lrow][wn >> 6] = vsj;
      }
    }
  }
  __syncthreads();
  if (tid < TM3) {
    int row = m0 + tid;
    if (row < M) {
      si[(size_t)row * HEADS + head] = rsi[tid][0] + rsi[tid][1];
      sj[(size_t)row * HEADS + head] = rsj[tid][0] + rsj[tid][1];
    }
  }
}

// ---------------------------------------------------------------------------
// CSR build
// ---------------------------------------------------------------------------
__global__ void count_kernel(const int* __restrict__ dst, int* __restrict__ deg, int E) {
  int e = blockIdx.x * blockDim.x + threadIdx.x;
  if (e < E) atomicAdd(&deg[dst[e]], 1);
}

__global__ __launch_bounds__(1024)
void scan_kernel(const int* __restrict__ deg, int* __restrict__ off, int N) {
  __shared__ int sums[1024];
  const int PER = 10;
  int tid = threadIdx.x;
  int base = tid * PER;
  int loc[PER];
  int run = 0;
  #pragma unroll
  for (int j = 0; j < PER; ++j) {
    int v = (base + j < N) ? deg[base + j] : 0;
    run += v;
    loc[j] = run;
  }
  sums[tid] = run;
  __syncthreads();
  for (int o = 1; o < 1024; o <<= 1) {
    int v = (tid >= o) ? sums[tid - o] : 0;
    __syncthreads();
    sums[tid] += v;
    __syncthreads();
  }
  int ex = sums[tid] - run;
  if (tid == 0) off[0] = 0;
  #pragma unroll
  for (int j = 0; j < PER; ++j)
    if (base + j < N) off[base + j + 1] = ex + loc[j];
}

__global__ void fill_kernel(const int* __restrict__ src, const int* __restrict__ dst,
                            const int* __restrict__ off, int* __restrict__ cursor,
                            int* __restrict__ ssrc, int E) {
  int e = blockIdx.x * blockDim.x + threadIdx.x;
  if (e < E) {
    int d = dst[e];
    int p = atomicAdd(&cursor[d], 1);
    ssrc[off[d] + p] = src[e];
  }
}

// ---------------------------------------------------------------------------
// Edge softmax weights: one wave per dst node. Lane = eidx*8 + head.
// ---------------------------------------------------------------------------
__global__ __launch_bounds__(256)
void alpha_kernel(const float* __restrict__ si, const float* __restrict__ sj,
                  const int* __restrict__ off, const int* __restrict__ ssrc,
                  float* __restrict__ w, float* __restrict__ invden, int N) {
  int wv = (blockIdx.x * blockDim.x + threadIdx.x) >> 6;
  if (wv >= N) return;
  int lane = threadIdx.x & 63;
  int eidx = lane >> 3, head = lane & 7;
  int begin = off[wv], end = off[wv + 1];
  float s_i = si[wv * HEADS + head];

  float m = -INFINITY;
  for (int k0 = begin; k0 < end; k0 += 8) {
    int k = k0 + eidx;
    if (k < end) {
      float e = s_i + sj[ssrc[k] * HEADS + head];
      e = e > 0.f ? e : 0.01f * e;
      m = fmaxf(m, e);
    }
  }
  m = fmaxf(m, __shfl_xor(m, 8));
  m = fmaxf(m, __shfl_xor(m, 16));
  m = fmaxf(m, __shfl_xor(m, 32));

  float sum = 0.f;
  for (int k0 = begin; k0 < end; k0 += 8) {
    int k = k0 + eidx;
    if (k < end) {
      float e = s_i + sj[ssrc[k] * HEADS + head];
      e = e > 0.f ? e : 0.01f * e;
      float wt = expf(e - m);
      w[(size_t)k * HEADS + head] = wt;
      sum += wt;
    }
  }
  sum += __shfl_xor(sum, 8);
  sum += __shfl_xor(sum, 16);
  sum += __shfl_xor(sum, 32);
  if (eidx == 0)
    invden[wv * HEADS + head] = sum > 0.f ? 1.0f / sum : 0.f;
}

// ---------------------------------------------------------------------------
// Aggregation v3: one wave per (dst, head); head = blockIdx.x & 7 (XCD/L2
// affinity). Wave = 4 groups x 16 lanes; each group one edge, each lane 16B.
// ---------------------------------------------------------------------------
__global__ __launch_bounds__(512)
void gat_aggregate3(const unsigned short* __restrict__ hb,
                    const float* __restrict__ w, const float* __restrict__ invden,
                    const int* __restrict__ off, const int* __restrict__ ssrc,
                    float* __restrict__ aggbuf, int N) {
  int head = blockIdx.x & 7;
  int n = (blockIdx.x >> 3) * 8 + (threadIdx.x >> 6);
  if (n >= N) return;
  int lane = threadIdx.x & 63;
  int grp = lane >> 4;
  int l = lane & 15;
  const unsigned short* hbase = hb + (size_t)head * N * HID;
  int begin = off[n], end = off[n + 1];

  float a0 = 0.f, a1 = 0.f, a2 = 0.f, a3 = 0.f;
  float a4 = 0.f, a5 = 0.f, a6 = 0.f, a7 = 0.f;

  for (int k0 = begin; k0 < end; k0 += 8) {
    int ka = k0 + grp;
    int kb = k0 + 4 + grp;
    int kka = ka < end ? ka : begin;
    int kkb = kb < end ? kb : begin;
    int sa = ssrc[kka];
    int sb = ssrc[kkb];
    float wa = w[(size_t)kka * HEADS + head];
    float wb = w[(size_t)kkb * HEADS + head];
    if (ka >= end) wa = 0.f;
    if (kb >= end) wb = 0.f;
    int4 pa = *(const int4*)&hbase[(size_t)sa * HID + l * 8];
    int4 pb = *(const int4*)&hbase[(size_t)sb * HID + l * 8];
    a0 = fmaf(wa, bf2f((unsigned)pa.x & 0xffffu), a0);
    a1 = fmaf(wa, __uint_as_float((unsigned)pa.x & 0xffff0000u), a1);
    a2 = fmaf(wa, bf2f((unsigned)pa.y & 0xffffu), a2);
    a3 = fmaf(wa, __uint_as_float((unsigned)pa.y & 0xffff0000u), a3);
    a4 = fmaf(wa, bf2f((unsigned)pa.z & 0xffffu), a4);
    a5 = fmaf(wa, __uint_as_float((unsigned)pa.z & 0xffff0000u), a5);
    a6 = fmaf(wa, bf2f((unsigned)pa.w & 0xffffu), a6);
    a7 = fmaf(wa, __uint_as_float((unsigned)pa.w & 0xffff0000u), a7);
    a0 = fmaf(wb, bf2f((unsigned)pb.x & 0xffffu), a0);
    a1 = fmaf(wb, __uint_as_float((unsigned)pb.x & 0xffff0000u), a1);
    a2 = fmaf(wb, bf2f((unsigned)pb.y & 0xffffu), a2);
    a3 = fmaf(wb, __uint_as_float((unsigned)pb.y & 0xffff0000u), a3);
    a4 = fmaf(wb, bf2f((unsigned)pb.z & 0xffffu), a4);
    a5 = fmaf(wb, __uint_as_float((unsigned)pb.z & 0xffff0000u), a5);
    a6 = fmaf(wb, bf2f((unsigned)pb.w & 0xffffu), a6);
    a7 = fmaf(wb, __uint_as_float((unsigned)pb.w & 0xffff0000u), a7);
  }
  a0 += __shfl_xor(a0, 16); a1 += __shfl_xor(a1, 16);
  a2 += __shfl_xor(a2, 16); a3 += __shfl_xor(a3, 16);
  a4 += __shfl_xor(a4, 16); a5 += __shfl_xor(a5, 16);
  a6 += __shfl_xor(a6, 16); a7 += __shfl_xor(a7, 16);
  a0 += __shfl_xor(a0, 32); a1 += __shfl_xor(a1, 32);
  a2 += __shfl_xor(a2, 32); a3 += __shfl_xor(a3, 32);
  a4 += __shfl_xor(a4, 32); a5 += __shfl_xor(a5, 32);
  a6 += __shfl_xor(a6, 32); a7 += __shfl_xor(a7, 32);

  if (grp == 0) {
    float inv = invden[n * HEADS + head];
    float* dst = aggbuf + ((size_t)head * N + n) * HID + l * 8;
    *(float4*)dst = make_float4(a0 * inv, a1 * inv, a2 * inv, a3 * inv);
    *(float4*)(dst + 4) = make_float4(a4 * inv, a5 * inv, a6 * inv, a7 * inv);
  }
}

// ---------------------------------------------------------------------------
// Head mean + ELU; mode bit0: write fp32 emb; bit1: write bf16 hi/lo split
// (fused layer-2 A-split; avoids a separate 10 MB round trip).
// ---------------------------------------------------------------------------
__global__ __launch_bounds__(256)
void headmean_kernel(const float* __restrict__ aggbuf, float* __restrict__ emb,
                     unsigned short* __restrict__ hi, unsigned short* __restrict__ lo,
                     int N, int mode) {
  int i = blockIdx.x * blockDim.x + threadIdx.x;
  if (i >= N * 64) return;
  float sx = 0.f, sy = 0.f;
  #pragma unroll
  for (int hh = 0; hh < HEADS; ++hh) {
    float2 v = ((const float2*)aggbuf)[(size_t)hh * N * 64 + i];
    sx += v.x; sy += v.y;
  }
  sx *= (1.0f / HEADS); sy *= (1.0f / HEADS);
  float ox = sx > 0.f ? sx : (expf(sx) - 1.0f);
  float oy = sy > 0.f ? sy : (expf(sy) - 1.0f);
  if (mode & 1)
    ((float2*)emb)[i] = make_float2(ox, oy);
  if (mode & 2) {
    ushort2 h, l;
    h.x = f2bf_rne(ox); l.x = f2bf_rne(ox - bf2f(h.x));
    h.y = f2bf_rne(oy); l.y = f2bf_rne(oy - bf2f(h.y));
    ((ushort2*)hi)[i] = h;
    ((ushort2*)lo)[i] = l;
  }
}

// ---------------------------------------------------------------------------
// Graph pooling
// ---------------------------------------------------------------------------
__global__ __launch_bounds__(256)
void pool_kernel(const float* __restrict__ emb, float* __restrict__ g, int N) {
  __shared__ float part[256];
  int d = threadIdx.x & 127;
  int half = threadIdx.x >> 7;
  int n0 = blockIdx.x * 100;
  float s = 0.f;
  for (int i = half; i < 100; i += 2) {
    int n = n0 + i;
    if (n < N) s += emb[(size_t)n * HID + d];
  }
  part[threadIdx.x] = s;
  __syncthreads();
  if (threadIdx.x < HID) atomicAdd(&g[d], part[threadIdx.x] + part[128 + threadIdx.x]);
}

// ---------------------------------------------------------------------------
// LayerNorm + MLP head
// ---------------------------------------------------------------------------
__global__ __launch_bounds__(128)
void mlp_kernel(const float* __restrict__ g, const float* __restrict__ ln_g,
                const float* __restrict__ ln_b, const float* __restrict__ Wl1,
                const float* __restrict__ bl1, const float* __restrict__ Wl2,
                const float* __restrict__ bl2, const float* __restrict__ Wl3,
                const float* __restrict__ bl3, float* __restrict__ out, float invN) {
  __shared__ float red[128];
  __shared__ float gn[128];
  __shared__ float x1[64];
  __shared__ float x2[16];
  int t = threadIdx.x;
  float gg = g[t] * invN;
  red[t] = gg;
  __syncthreads();
  for (int o = 64; o > 0; o >>= 1) {
    if (t < o) red[t] += red[t + o];
    __syncthreads();
  }
  float mu = red[0] * (1.0f / HID);
  __syncthreads();
  float dv = gg - mu;
  red[t] = dv * dv;
  __syncthreads();
  for (int o = 64; o > 0; o >>= 1) {
    if (t < o) red[t] += red[t + o];
    __syncthreads();
  }
  float var = red[0] * (1.0f / HID);
  gn[t] = dv / sqrtf(var + 1e-5f) * ln_g[t] + ln_b[t];
  __syncthreads();
  if (t < 64) {
    float s = bl1[t];
    for (int k = 0; k < 128; ++k) s += Wl1[t * 128 + k] * gn[k];
    x1[t] = s > 0.f ? s : 0.01f * s;
  }
  __syncthreads();
  if (t < 16) {
    float s = bl2[t];
    for (int k = 0; k < 64; ++k) s += Wl2[t * 64 + k] * x1[k];
    x2[t] = s > 0.f ? s : 0.01f * s;
  }
  __syncthreads();
  if (t < 16) {
    float s = bl3[t];
    for (int k = 0; k < 16; ++k) s += Wl3[t * 16 + k] * x2[k];
    out[t] = s > 0.f ? s : 0.f;
  }
}

// ---------------------------------------------------------------------------
extern "C" void kernel_launch(void* const* d_in, const int* in_sizes, int n_in,
                              void* d_out, int out_size, void* d_ws, size_t ws_size,
                              hipStream_t stream) {
  const float* x    = (const float*)d_in[0];
  const int*   esrc = (const int*)d_in[1];
  const int*   edst = (const int*)d_in[2];
  const float* W1   = (const float*)d_in[3];
  const float* a1   = (const float*)d_in[4];
  const float* W2   = (const float*)d_in[5];
  const float* a2   = (const float*)d_in[6];
  const float* ln_g = (const float*)d_in[7];
  const float* ln_b = (const float*)d_in[8];
  const float* Wl1  = (const float*)d_in[9];
  const float* bl1  = (const float*)d_in[10];
  const float* Wl2  = (const float*)d_in[11];
  const float* bl2  = (const float*)d_in[12];
  const float* Wl3  = (const float*)d_in[13];
  const float* bl3  = (const float*)d_in[14];
  float* out = (float*)d_out;

  float* ws   = (float*)d_ws;
  float* aggbuf = ws;                                   // 10,240,000 f (41 MB)
  float* si   = aggbuf + (size_t)N_NODES * HEADS * HID; // 80,000
  float* sj   = si + N_NODES * HEADS;                   // 80,000
  float* emb2 = sj + N_NODES * HEADS;                   // 1,280,000
  float* g    = emb2 + (size_t)N_NODES * HID;           // 128
  float* wbuf = g + 128;                                // 1,280,000
  float* invd = wbuf + (size_t)N_EDGES * HEADS;         // 80,000
  int*   deg  = (int*)(invd + N_NODES * HEADS);         // 10,000
  int*   off  = deg + N_NODES;                          // 10,001
  int*   ssrc = off + (N_NODES + 1);                    // 160,000
  unsigned short* sAhi = (unsigned short*)(ssrc + N_EDGES + 3);
  unsigned short* sAlo = sAhi + (size_t)N_NODES * N_FEAT;
  unsigned short* sBhi = sAlo + (size_t)N_NODES * N_FEAT;
  unsigned short* sBlo = sBhi + HEADS * HID * N_FEAT;
  unsigned short* hb   = sBlo + HEADS * HID * N_FEAT;   // 20.5 MB

  // CSR by dst
  hipMemsetAsync(deg, 0, N_NODES * sizeof(int), stream);
  count_kernel<<<(N_EDGES + 255) / 256, 256, 0, stream>>>(edst, deg, N_EDGES);
  scan_kernel<<<1, 1024, 0, stream>>>(deg, off, N_NODES);
  hipMemsetAsync(deg, 0, N_NODES * sizeof(int), stream);
  fill_kernel<<<(N_EDGES + 255) / 256, 256, 0, stream>>>(esrc, edst, off, deg, ssrc, N_EDGES);

  int nMTiles = (N_NODES + TM3 - 1) / TM3;        // 79
  int nMTilesPad = ((nMTiles + 7) / 8) * 8;       // 80
  int gemmGrid = nMTilesPad * HEADS;              // 640
  int aggGrid = (N_NODES / 8) * 8;
  int hmGrid = (N_NODES * 64 + 255) / 256;

  // ---- Layer 1 ----
  {
    int n4 = N_NODES * N_FEAT / 4;
    split_kernel<<<(n4 + 255) / 256, 256, 0, stream>>>(x, sAhi, sAlo, n4);
    int w4 = HEADS * HID * N_FEAT / 4;
    split_kernel<<<(w4 + 255) / 256, 256, 0, stream>>>(W1, sBhi, sBlo, w4);
    gemm_mfma_split3<<<gemmGrid, 256, 0, stream>>>(sAhi, sAlo, sBhi, sBlo, a1, hb,
                                                   si, sj, N_NODES, N_FEAT);
  }
  alpha_kernel<<<(N_NODES + 3) / 4, 256, 0, stream>>>(si, sj, off, ssrc, wbuf, invd, N_NODES);
  gat_aggregate3<<<aggGrid, 512, 0, stream>>>(hb, wbuf, invd, off, ssrc, aggbuf, N_NODES);
  // fused layer-2 A split (emb1 fp32 never materialized)
  headmean_kernel<<<hmGrid, 256, 0, stream>>>(aggbuf, nullptr, sAhi, sAlo, N_NODES, 2);

  // ---- Layer 2 ----
  {
    int w4 = HEADS * HID * HID / 4;
    split_kernel<<<(w4 + 255) / 256, 256, 0, stream>>>(W2, sBhi, sBlo, w4);
    gemm_mfma_split3<<<gemmGrid, 256, 0, stream>>>(sAhi, sAlo, sBhi, sBlo, a2, hb,
                                                   si, sj, N_NODES, HID);
  }
  alpha_kernel<<<(N_NODES + 3) / 4, 256, 0, stream>>>(si, sj, off, ssrc, wbuf, invd, N_NODES);
  gat_aggregate3<<<aggGrid, 512, 0, stream>>>(hb, wbuf, invd, off, ssrc, aggbuf, N_NODES);
  headmean_kernel<<<hmGrid, 256, 0, stream>>>(aggbuf, emb2, nullptr, nullptr, N_NODES, 1);

  // ---- Pool + MLP head ----
  hipMemsetAsync(g, 0, HID * sizeof(float), stream);
  pool_kernel<<<100, 256, 0, stream>>>(emb2, g, N_NODES);
  mlp_kernel<<<1, 128, 0, stream>>>(g, ln_g, ln_b, Wl1, bl1, Wl2, bl2, Wl3, bl3,
                                    out, 1.0f / N_NODES);
}

// Round 8
// 332.429 us; speedup vs baseline: 1.3861x; 1.0662x over previous
//
#include <hip/hip_runtime.h>
#include <math.h>

#define N_NODES 10000
#define N_EDGES 160000
#define N_FEAT  512
#define HEADS   8
#define HID     128

typedef __attribute__((ext_vector_type(8))) short bf16x8;
typedef __attribute__((ext_vector_type(4))) float f32x4;

// ---------------------------------------------------------------------------
// fp32 <-> bf16 helpers
// ---------------------------------------------------------------------------
__device__ inline unsigned short f2bf_rne(float f) {
  unsigned int u = __float_as_uint(f);
  unsigned int r = u + 0x7fffu + ((u >> 16) & 1u);
  return (unsigned short)(r >> 16);
}
__device__ inline float bf2f(unsigned int b) {
  return __uint_as_float(b << 16);
}

// ---------------------------------------------------------------------------
// Split fp32 [R][K] into hi/lo bf16 in MFMA-fragment-major layout:
// unit (rb,kq,r) at index (rb*K8+kq)*16+r holds 8 bf16 = A[rb*16+r][kq*8..+8].
// A wave's frag load (lane q*16+r reads unit (rb, kq0+q, r)) is then one
// fully-coalesced 1KB global_load_dwordx4 burst. Rows >= R are zero-filled.
// ---------------------------------------------------------------------------
__global__ __launch_bounds__(256)
void split_frag(const float* __restrict__ in, unsigned short* __restrict__ hi,
                unsigned short* __restrict__ lo, int R, int K8, int total) {
  int idx = blockIdx.x * 256 + threadIdx.x;
  if (idx >= total) return;
  int r = idx & 15;
  int t = idx >> 4;
  int kq = t % K8;
  int rb = t / K8;
  int row = rb * 16 + r;
  float v[8] = {0.f, 0.f, 0.f, 0.f, 0.f, 0.f, 0.f, 0.f};
  if (row < R) {
    const float* p = in + (size_t)row * (K8 * 8) + kq * 8;
    float4 a = *(const float4*)p;
    float4 b = *(const float4*)(p + 4);
    v[0] = a.x; v[1] = a.y; v[2] = a.z; v[3] = a.w;
    v[4] = b.x; v[5] = b.y; v[6] = b.z; v[7] = b.w;
  }
  union { unsigned short u[8]; int4 v4; } H, L;
  #pragma unroll
  for (int e = 0; e < 8; ++e) {
    unsigned short hb_ = f2bf_rne(v[e]);
    H.u[e] = hb_;
    L.u[e] = f2bf_rne(v[e] - bf2f(hb_));
  }
  *(int4*)&hi[(size_t)idx * 8] = H.v4;
  *(int4*)&lo[(size_t)idx * 8] = L.v4;
}

// ---------------------------------------------------------------------------
// LDS-free split-bf16 MFMA GEMM: block = 64 rows x 128 cols (one full head),
// 2 waves (wn 0/64) sharing identical A-frags (L1 reuse). All fragments read
// directly from global in frag-major layout -> no LDS staging, no K-loop
// barriers: 16 independent b128 loads + 48 MFMAs per K-iter per wave.
// Grid 160*8 swizzled: blk%8 == mtile%8 (8 head-blocks of an m-tile share an
// XCD's L2 for A; B (<=2MB) stays L2-resident).
// Epilogue: fused si/sj scores + bf16 hb (head-major) write.
// ---------------------------------------------------------------------------
__global__ __launch_bounds__(128, 3)
void gemm_frag(const unsigned short* __restrict__ Afh,
               const unsigned short* __restrict__ Afl,
               const unsigned short* __restrict__ Bfh,
               const unsigned short* __restrict__ Bfl,
               const float* __restrict__ avec,
               unsigned short* __restrict__ hb,
               float* __restrict__ si, float* __restrict__ sj,
               int M, int K) {
  __shared__ float rsi[64][2];
  __shared__ float rsj[64][2];
  int tid = threadIdx.x;
  int wave = tid >> 6, lane = tid & 63;
  int r = lane & 15, q = lane >> 4;

  int blk = blockIdx.x;
  int rr = blk & 7, gg = blk >> 3;
  int head = gg & 7;
  int mtile = (gg >> 3) * 8 + rr;     // blk%8 == mtile%8 -> XCD affinity
  int m0 = mtile * 64;
  int wn = wave * 64;
  int K8 = K >> 3;

  const bf16x8* pAh = (const bf16x8*)Afh;
  const bf16x8* pAl = (const bf16x8*)Afl;
  const bf16x8* pBh = (const bf16x8*)Bfh;
  const bf16x8* pBl = (const bf16x8*)Bfl;
  size_t rstep = (size_t)K8 * 16;
  size_t aidx = (size_t)(m0 >> 4) * rstep + (size_t)q * 16 + r;
  size_t bidx = (size_t)(head * 8 + (wn >> 4)) * rstep + (size_t)q * 16 + r;

  f32x4 acc[4][4] = {};

  for (int k0 = 0; k0 < K; k0 += 32, aidx += 64, bidx += 64) {
    bf16x8 ah[4], al[4], bh[4], bl[4];
    #pragma unroll
    for (int i = 0; i < 4; ++i) {
      ah[i] = pAh[aidx + i * rstep];
      al[i] = pAl[aidx + i * rstep];
      bh[i] = pBh[bidx + i * rstep];
      bl[i] = pBl[bidx + i * rstep];
    }
    #pragma unroll
    for (int i = 0; i < 4; ++i)
      #pragma unroll
      for (int j = 0; j < 4; ++j) {
        acc[i][j] = __builtin_amdgcn_mfma_f32_16x16x32_bf16(ah[i], bh[j], acc[i][j], 0, 0, 0);
        acc[i][j] = __builtin_amdgcn_mfma_f32_16x16x32_bf16(ah[i], bl[j], acc[i][j], 0, 0, 0);
        acc[i][j] = __builtin_amdgcn_mfma_f32_16x16x32_bf16(al[i], bh[j], acc[i][j], 0, 0, 0);
      }
  }

  // --- epilogue: C/D layout col = r, row = q*4 + reg (per 16x16 frag) ---
  const float* av = avec + (size_t)head * (2 * HID);
  float aiv[4], ajv[4];
  #pragma unroll
  for (int j = 0; j < 4; ++j) {
    int c = wn + j * 16 + r;
    aiv[j] = av[c];
    ajv[j] = av[HID + c];
  }
  #pragma unroll
  for (int i = 0; i < 4; ++i) {
    #pragma unroll
    for (int reg = 0; reg < 4; ++reg) {
      int lrow = i * 16 + q * 4 + reg;
      int row = m0 + lrow;
      float vsi = 0.f, vsj = 0.f;
      #pragma unroll
      for (int j = 0; j < 4; ++j) {
        float v = acc[i][j][reg];
        vsi = fmaf(v, aiv[j], vsi);
        vsj = fmaf(v, ajv[j], vsj);
        if (row < M)
          hb[((size_t)head * M + row) * HID + wn + j * 16 + r] = f2bf_rne(v);
      }
      #pragma unroll
      for (int o = 8; o >= 1; o >>= 1) {
        vsi += __shfl_xor(vsi, o);
        vsj += __shfl_xor(vsj, o);
      }
      if (r == 0) {
        rsi[lrow][wave] = vsi;
        rsj[lrow][wave] = vsj;
      }
    }
  }
  __syncthreads();
  if (tid < 64) {
    int row = m0 + tid;
    if (row < M) {
      si[(size_t)row * HEADS + head] = rsi[tid][0] + rsi[tid][1];
      sj[(size_t)row * HEADS + head] = rsj[tid][0] + rsj[tid][1];
    }
  }
}

// ---------------------------------------------------------------------------
// CSR build
// ---------------------------------------------------------------------------
__global__ void count_kernel(const int* __restrict__ dst, int* __restrict__ deg, int E) {
  int e = blockIdx.x * blockDim.x + threadIdx.x;
  if (e < E) atomicAdd(&deg[dst[e]], 1);
}

__global__ __launch_bounds__(1024)
void scan_kernel(const int* __restrict__ deg, int* __restrict__ off, int N) {
  __shared__ int sums[1024];
  const int PER = 10;
  int tid = threadIdx.x;
  int base = tid * PER;
  int loc[PER];
  int run = 0;
  #pragma unroll
  for (int j = 0; j < PER; ++j) {
    int v = (base + j < N) ? deg[base + j] : 0;
    run += v;
    loc[j] = run;
  }
  sums[tid] = run;
  __syncthreads();
  for (int o = 1; o < 1024; o <<= 1) {
    int v = (tid >= o) ? sums[tid - o] : 0;
    __syncthreads();
    sums[tid] += v;
    __syncthreads();
  }
  int ex = sums[tid] - run;
  if (tid == 0) off[0] = 0;
  #pragma unroll
  for (int j = 0; j < PER; ++j)
    if (base + j < N) off[base + j + 1] = ex + loc[j];
}

__global__ void fill_kernel(const int* __restrict__ src, const int* __restrict__ dst,
                            const int* __restrict__ off, int* __restrict__ cursor,
                            int* __restrict__ ssrc, int E) {
  int e = blockIdx.x * blockDim.x + threadIdx.x;
  if (e < E) {
    int d = dst[e];
    int p = atomicAdd(&cursor[d], 1);
    ssrc[off[d] + p] = src[e];
  }
}

// ---------------------------------------------------------------------------
// Edge softmax weights: one wave per dst node. Lane = eidx*8 + head.
// ---------------------------------------------------------------------------
__global__ __launch_bounds__(256)
void alpha_kernel(const float* __restrict__ si, const float* __restrict__ sj,
                  const int* __restrict__ off, const int* __restrict__ ssrc,
                  float* __restrict__ w, float* __restrict__ invden, int N) {
  int wv = (blockIdx.x * blockDim.x + threadIdx.x) >> 6;
  if (wv >= N) return;
  int lane = threadIdx.x & 63;
  int eidx = lane >> 3, head = lane & 7;
  int begin = off[wv], end = off[wv + 1];
  float s_i = si[wv * HEADS + head];

  float m = -INFINITY;
  for (int k0 = begin; k0 < end; k0 += 8) {
    int k = k0 + eidx;
    if (k < end) {
      float e = s_i + sj[ssrc[k] * HEADS + head];
      e = e > 0.f ? e : 0.01f * e;
      m = fmaxf(m, e);
    }
  }
  m = fmaxf(m, __shfl_xor(m, 8));
  m = fmaxf(m, __shfl_xor(m, 16));
  m = fmaxf(m, __shfl_xor(m, 32));

  float sum = 0.f;
  for (int k0 = begin; k0 < end; k0 += 8) {
    int k = k0 + eidx;
    if (k < end) {
      float e = s_i + sj[ssrc[k] * HEADS + head];
      e = e > 0.f ? e : 0.01f * e;
      float wt = expf(e - m);
      w[(size_t)k * HEADS + head] = wt;
      sum += wt;
    }
  }
  sum += __shfl_xor(sum, 8);
  sum += __shfl_xor(sum, 16);
  sum += __shfl_xor(sum, 32);
  if (eidx == 0)
    invden[wv * HEADS + head] = sum > 0.f ? 1.0f / sum : 0.f;
}

// ---------------------------------------------------------------------------
// Aggregation: one wave per (dst, head); head = blockIdx.x & 7 (XCD/L2
// affinity). Wave = 4 groups x 16 lanes; each group one edge, each lane 16B.
// ---------------------------------------------------------------------------
__global__ __launch_bounds__(512)
void gat_aggregate3(const unsigned short* __restrict__ hb,
                    const float* __restrict__ w, const float* __restrict__ invden,
                    const int* __restrict__ off, const int* __restrict__ ssrc,
                    float* __restrict__ aggbuf, int N) {
  int head = blockIdx.x & 7;
  int n = (blockIdx.x >> 3) * 8 + (threadIdx.x >> 6);
  if (n >= N) return;
  int lane = threadIdx.x & 63;
  int grp = lane >> 4;
  int l = lane & 15;
  const unsigned short* hbase = hb + (size_t)head * N * HID;
  int begin = off[n], end = off[n + 1];

  float a0 = 0.f, a1 = 0.f, a2 = 0.f, a3 = 0.f;
  float a4 = 0.f, a5 = 0.f, a6 = 0.f, a7 = 0.f;

  for (int k0 = begin; k0 < end; k0 += 8) {
    int ka = k0 + grp;
    int kb = k0 + 4 + grp;
    int kka = ka < end ? ka : begin;
    int kkb = kb < end ? kb : begin;
    int sa = ssrc[kka];
    int sb = ssrc[kkb];
    float wa = w[(size_t)kka * HEADS + head];
    float wb = w[(size_t)kkb * HEADS + head];
    if (ka >= end) wa = 0.f;
    if (kb >= end) wb = 0.f;
    int4 pa = *(const int4*)&hbase[(size_t)sa * HID + l * 8];
    int4 pb = *(const int4*)&hbase[(size_t)sb * HID + l * 8];
    a0 = fmaf(wa, bf2f((unsigned)pa.x & 0xffffu), a0);
    a1 = fmaf(wa, __uint_as_float((unsigned)pa.x & 0xffff0000u), a1);
    a2 = fmaf(wa, bf2f((unsigned)pa.y & 0xffffu), a2);
    a3 = fmaf(wa, __uint_as_float((unsigned)pa.y & 0xffff0000u), a3);
    a4 = fmaf(wa, bf2f((unsigned)pa.z & 0xffffu), a4);
    a5 = fmaf(wa, __uint_as_float((unsigned)pa.z & 0xffff0000u), a5);
    a6 = fmaf(wa, bf2f((unsigned)pa.w & 0xffffu), a6);
    a7 = fmaf(wa, __uint_as_float((unsigned)pa.w & 0xffff0000u), a7);
    a0 = fmaf(wb, bf2f((unsigned)pb.x & 0xffffu), a0);
    a1 = fmaf(wb, __uint_as_float((unsigned)pb.x & 0xffff0000u), a1);
    a2 = fmaf(wb, bf2f((unsigned)pb.y & 0xffffu), a2);
    a3 = fmaf(wb, __uint_as_float((unsigned)pb.y & 0xffff0000u), a3);
    a4 = fmaf(wb, bf2f((unsigned)pb.z & 0xffffu), a4);
    a5 = fmaf(wb, __uint_as_float((unsigned)pb.z & 0xffff0000u), a5);
    a6 = fmaf(wb, bf2f((unsigned)pb.w & 0xffffu), a6);
    a7 = fmaf(wb, __uint_as_float((unsigned)pb.w & 0xffff0000u), a7);
  }
  a0 += __shfl_xor(a0, 16); a1 += __shfl_xor(a1, 16);
  a2 += __shfl_xor(a2, 16); a3 += __shfl_xor(a3, 16);
  a4 += __shfl_xor(a4, 16); a5 += __shfl_xor(a5, 16);
  a6 += __shfl_xor(a6, 16); a7 += __shfl_xor(a7, 16);
  a0 += __shfl_xor(a0, 32); a1 += __shfl_xor(a1, 32);
  a2 += __shfl_xor(a2, 32); a3 += __shfl_xor(a3, 32);
  a4 += __shfl_xor(a4, 32); a5 += __shfl_xor(a5, 32);
  a6 += __shfl_xor(a6, 32); a7 += __shfl_xor(a7, 32);

  if (grp == 0) {
    float inv = invden[n * HEADS + head];
    float* dst = aggbuf + ((size_t)head * N + n) * HID + l * 8;
    *(float4*)dst = make_float4(a0 * inv, a1 * inv, a2 * inv, a3 * inv);
    *(float4*)(dst + 4) = make_float4(a4 * inv, a5 * inv, a6 * inv, a7 * inv);
  }
}

// ---------------------------------------------------------------------------
// Head mean + ELU, writing layer-2 A directly in frag-major split form
// (K8 = HID/8 = 16). unit (rb,kq,r) holds emb1[rb*16+r][kq*8..+8].
// ---------------------------------------------------------------------------
__global__ __launch_bounds__(256)
void headmean_frag(const float* __restrict__ aggbuf, unsigned short* __restrict__ hi,
                   unsigned short* __restrict__ lo, int N) {
  int idx = blockIdx.x * 256 + threadIdx.x;   // (rb,kq,r), K8=16
  int total = ((N + 15) / 16) * 256;
  if (idx >= total) return;
  int r = idx & 15;
  int kq = (idx >> 4) & 15;
  int rb = idx >> 8;
  int n = rb * 16 + r;
  float s[8] = {0.f, 0.f, 0.f, 0.f, 0.f, 0.f, 0.f, 0.f};
  if (n < N) {
    #pragma unroll
    for (int hh = 0; hh < HEADS; ++hh) {
      const float* p = aggbuf + ((size_t)hh * N + n) * HID + kq * 8;
      float4 p0 = *(const float4*)p;
      float4 p1 = *(const float4*)(p + 4);
      s[0] += p0.x; s[1] += p0.y; s[2] += p0.z; s[3] += p0.w;
      s[4] += p1.x; s[5] += p1.y; s[6] += p1.z; s[7] += p1.w;
    }
  }
  union { unsigned short u[8]; int4 v4; } H, L;
  #pragma unroll
  for (int e = 0; e < 8; ++e) {
    float v = s[e] * (1.0f / HEADS);
    v = v > 0.f ? v : (expf(v) - 1.0f);   // ELU
    unsigned short hb_ = f2bf_rne(v);
    H.u[e] = hb_;
    L.u[e] = f2bf_rne(v - bf2f(hb_));
  }
  *(int4*)&hi[(size_t)idx * 8] = H.v4;
  *(int4*)&lo[(size_t)idx * 8] = L.v4;
}

// ---------------------------------------------------------------------------
// Head mean + ELU -> fp32 emb (layer 2 output, feeds pooling)
// ---------------------------------------------------------------------------
__global__ __launch_bounds__(256)
void headmean_emb(const float* __restrict__ aggbuf, float* __restrict__ emb, int N) {
  int i = blockIdx.x * blockDim.x + threadIdx.x;
  if (i >= N * 64) return;
  float sx = 0.f, sy = 0.f;
  #pragma unroll
  for (int hh = 0; hh < HEADS; ++hh) {
    float2 v = ((const float2*)aggbuf)[(size_t)hh * N * 64 + i];
    sx += v.x; sy += v.y;
  }
  sx *= (1.0f / HEADS); sy *= (1.0f / HEADS);
  float ox = sx > 0.f ? sx : (expf(sx) - 1.0f);
  float oy = sy > 0.f ? sy : (expf(sy) - 1.0f);
  ((float2*)emb)[i] = make_float2(ox, oy);
}

// ---------------------------------------------------------------------------
// Graph pooling
// ---------------------------------------------------------------------------
__global__ __launch_bounds__(256)
void pool_kernel(const float* __restrict__ emb, float* __restrict__ g, int N) {
  __shared__ float part[256];
  int d = threadIdx.x & 127;
  int half = threadIdx.x >> 7;
  int n0 = blockIdx.x * 100;
  float s = 0.f;
  for (int i = half; i < 100; i += 2) {
    int n = n0 + i;
    if (n < N) s += emb[(size_t)n * HID + d];
  }
  part[threadIdx.x] = s;
  __syncthreads();
  if (threadIdx.x < HID) atomicAdd(&g[d], part[threadIdx.x] + part[128 + threadIdx.x]);
}

// ---------------------------------------------------------------------------
// LayerNorm + MLP head
// ---------------------------------------------------------------------------
__global__ __launch_bounds__(128)
void mlp_kernel(const float* __restrict__ g, const float* __restrict__ ln_g,
                const float* __restrict__ ln_b, const float* __restrict__ Wl1,
                const float* __restrict__ bl1, const float* __restrict__ Wl2,
                const float* __restrict__ bl2, const float* __restrict__ Wl3,
                const float* __restrict__ bl3, float* __restrict__ out, float invN) {
  __shared__ float red[128];
  __shared__ float gn[128];
  __shared__ float x1[64];
  __shared__ float x2[16];
  int t = threadIdx.x;
  float gg = g[t] * invN;
  red[t] = gg;
  __syncthreads();
  for (int o = 64; o > 0; o >>= 1) {
    if (t < o) red[t] += red[t + o];
    __syncthreads();
  }
  float mu = red[0] * (1.0f / HID);
  __syncthreads();
  float dv = gg - mu;
  red[t] = dv * dv;
  __syncthreads();
  for (int o = 64; o > 0; o >>= 1) {
    if (t < o) red[t] += red[t + o];
    __syncthreads();
  }
  float var = red[0] * (1.0f / HID);
  gn[t] = dv / sqrtf(var + 1e-5f) * ln_g[t] + ln_b[t];
  __syncthreads();
  if (t < 64) {
    float s = bl1[t];
    for (int k = 0; k < 128; ++k) s += Wl1[t * 128 + k] * gn[k];
    x1[t] = s > 0.f ? s : 0.01f * s;
  }
  __syncthreads();
  if (t < 16) {
    float s = bl2[t];
    for (int k = 0; k < 64; ++k) s += Wl2[t * 64 + k] * x1[k];
    x2[t] = s > 0.f ? s : 0.01f * s;
  }
  __syncthreads();
  if (t < 16) {
    float s = bl3[t];
    for (int k = 0; k < 16; ++k) s += Wl3[t * 16 + k] * x2[k];
    out[t] = s > 0.f ? s : 0.f;
  }
}

// ---------------------------------------------------------------------------
extern "C" void kernel_launch(void* const* d_in, const int* in_sizes, int n_in,
                              void* d_out, int out_size, void* d_ws, size_t ws_size,
                              hipStream_t stream) {
  const float* x    = (const float*)d_in[0];
  const int*   esrc = (const int*)d_in[1];
  const int*   edst = (const int*)d_in[2];
  const float* W1   = (const float*)d_in[3];
  const float* a1   = (const float*)d_in[4];
  const float* W2   = (const float*)d_in[5];
  const float* a2   = (const float*)d_in[6];
  const float* ln_g = (const float*)d_in[7];
  const float* ln_b = (const float*)d_in[8];
  const float* Wl1  = (const float*)d_in[9];
  const float* bl1  = (const float*)d_in[10];
  const float* Wl2  = (const float*)d_in[11];
  const float* bl2  = (const float*)d_in[12];
  const float* Wl3  = (const float*)d_in[13];
  const float* bl3  = (const float*)d_in[14];
  float* out = (float*)d_out;

  // rows padded to 640 row-blocks (10240 rows) so all frag reads are in-bounds
  const int RBPAD = 640;

  float* ws   = (float*)d_ws;
  float* aggbuf = ws;                                   // 10,240,000 f (41 MB)
  float* si   = aggbuf + (size_t)N_NODES * HEADS * HID; // 80,000
  float* sj   = si + N_NODES * HEADS;                   // 80,000
  float* emb2 = sj + N_NODES * HEADS;                   // 1,280,000
  float* g    = emb2 + (size_t)N_NODES * HID;           // 128
  float* wbuf = g + 128;                                // 1,280,000
  float* invd = wbuf + (size_t)N_EDGES * HEADS;         // 80,000
  int*   deg  = (int*)(invd + N_NODES * HEADS);         // 10,000
  int*   off  = deg + N_NODES;                          // 10,001
  int*   ssrc = off + (N_NODES + 1);                    // 160,000
  unsigned short* Afh = (unsigned short*)(ssrc + N_EDGES + 3);  // 640*64*128 us = 5,242,880
  unsigned short* Afl = Afh + (size_t)RBPAD * 64 * 128;
  unsigned short* Bfh = Afl + (size_t)RBPAD * 64 * 128;         // 64*64*128 = 524,288
  unsigned short* Bfl = Bfh + (size_t)64 * 64 * 128;
  unsigned short* hb  = Bfl + (size_t)64 * 64 * 128;            // 10,240,000 us (20.5 MB)

  // CSR by dst
  hipMemsetAsync(deg, 0, N_NODES * sizeof(int), stream);
  count_kernel<<<(N_EDGES + 255) / 256, 256, 0, stream>>>(edst, deg, N_EDGES);
  scan_kernel<<<1, 1024, 0, stream>>>(deg, off, N_NODES);
  hipMemsetAsync(deg, 0, N_NODES * sizeof(int), stream);
  fill_kernel<<<(N_EDGES + 255) / 256, 256, 0, stream>>>(esrc, edst, off, deg, ssrc, N_EDGES);

  int gemmGrid = 160 * HEADS;                 // 1280 blocks of 128 threads
  int aggGrid = (N_NODES / 8) * 8;
  int hmGrid = (N_NODES * 64 + 255) / 256;

  // ---- Layer 1 ----
  {
    int totalA = RBPAD * 64 * 16;             // 16B units, K8=64
    split_frag<<<(totalA + 255) / 256, 256, 0, stream>>>(x, Afh, Afl, N_NODES, 64, totalA);
    int totalB = 64 * 64 * 16;                // 1024 rows, K8=64
    split_frag<<<(totalB + 255) / 256, 256, 0, stream>>>(W1, Bfh, Bfl, HEADS * HID, 64, totalB);
    gemm_frag<<<gemmGrid, 128, 0, stream>>>(Afh, Afl, Bfh, Bfl, a1, hb,
                                            si, sj, N_NODES, N_FEAT);
  }
  alpha_kernel<<<(N_NODES + 3) / 4, 256, 0, stream>>>(si, sj, off, ssrc, wbuf, invd, N_NODES);
  gat_aggregate3<<<aggGrid, 512, 0, stream>>>(hb, wbuf, invd, off, ssrc, aggbuf, N_NODES);
  // layer-2 A written directly in frag-major split form (K8 = 16)
  {
    int totalHM = ((N_NODES + 15) / 16) * 256;
    headmean_frag<<<(totalHM + 255) / 256, 256, 0, stream>>>(aggbuf, Afh, Afl, N_NODES);
  }

  // ---- Layer 2 ----
  {
    int totalB = 64 * 16 * 16;                // 1024 rows, K8=16
    split_frag<<<(totalB + 255) / 256, 256, 0, stream>>>(W2, Bfh, Bfl, HEADS * HID, 16, totalB);
    gemm_frag<<<gemmGrid, 128, 0, stream>>>(Afh, Afl, Bfh, Bfl, a2, hb,
                                            si, sj, N_NODES, HID);
  }
  alpha_kernel<<<(N_NODES + 3) / 4, 256, 0, stream>>>(si, sj, off, ssrc, wbuf, invd, N_NODES);
  gat_aggregate3<<<aggGrid, 512, 0, stream>>>(hb, wbuf, invd, off, ssrc, aggbuf, N_NODES);
  headmean_emb<<<hmGrid, 256, 0, stream>>>(aggbuf, emb2, N_NODES);

  // ---- Pool + MLP head ----
  hipMemsetAsync(g, 0, HID * sizeof(float), stream);
  pool_kernel<<<100, 256, 0, stream>>>(emb2, g, N_NODES);
  mlp_kernel<<<1, 128, 0, stream>>>(g, ln_g, ln_b, Wl1, bl1, Wl2, bl2, Wl3, bl3,
                                    out, 1.0f / N_NODES);
}